// Round 10
// baseline (1674.659 us; speedup 1.0000x reference)
//
#include <hip/hip_runtime.h>

namespace {

constexpr int Hn = 128, Wn = 128, HWn = 16384, HWFn = 8320;
constexpr float TWOPI = 6.2831853071795864769f;
constexpr float BN_SCALE = 0.99999500003749968f;   // 1/sqrt(1+1e-5)

typedef __attribute__((ext_vector_type(8))) short short8;
typedef __attribute__((ext_vector_type(4))) float float4v;

__device__ __forceinline__ short f2bf(float v){
  unsigned u = __float_as_uint(v);
  u += 0x7FFF + ((u >> 16) & 1);          // RNE
  return (short)(u >> 16);
}
__device__ __forceinline__ float bf2f(unsigned short u){
  return __uint_as_float(((unsigned)u) << 16);
}

// ---------- weight pack to MFMA A-frag order (bf16), 3x3 convs ----------
__global__ void k_pack(const float* __restrict__ w, unsigned short* __restrict__ o,
                       int Cin, int csz, int n){
  int idx = blockIdx.x*256 + threadIdx.x;
  if (idx >= n) return;
  int ck = idx / csz;
  int i  = idx - ck*csz;
  const float* wp = w + (size_t)ck*csz;
  int j = i & 7, lane = (i>>3)&63, mt = (i>>9)&3, p = i>>11;
  int blk = p/18, r = p - blk*18, tap = r>>1, ks = r&1;
  int co = mt*16 + (lane & 15);
  int ci = blk*64 + ks*32 + ((lane>>4)<<3) + j;
  o[idx] = (unsigned short)f2bf(wp[((size_t)co*Cin + ci)*9 + tap]);
}

// ---------- weight pack for 1x1 (Cin=64): blocks ordered ks*MT+mt ----------
__global__ void k_packpw(const float* __restrict__ w, unsigned short* __restrict__ o,
                         int Cout, int MT, int n){
  int i = blockIdx.x*256 + threadIdx.x;
  if (i >= n) return;
  int per = MT << 10;                 // 2*MT*512
  int set = i / per;
  int r = i - set*per;
  int j = r & 7, lane = (r>>3)&63, blk = r>>9;
  int ks = blk / MT, mt = blk - ks*MT;
  int co = mt*16 + (lane & 15);
  int ci = ks*32 + ((lane>>4)<<3) + j;
  float v = (co < Cout) ? w[(size_t)set*Cout*64 + co*64 + ci] : 0.f;
  o[i] = (unsigned short)f2bf(v);
}

// ---------- weight transform for fused fd1/fd2/fconv chain ----------
__global__ void k_wfdc(const float* __restrict__ fd1w, const float* __restrict__ fd2w,
                       const float* __restrict__ fcw,  const float* __restrict__ fd1g,
                       const float* __restrict__ fd2g, float* __restrict__ o){
  int i = blockIdx.x*256 + threadIdx.x;   // 2*13312
  if (i >= 26624) return;
  int br = i / 13312, r = i - br*13312;
  float v;
  if (r < 2048){
    int ci = r >> 5, j = r & 31;
    v = fd1w[br*2048 + j*64 + ci] * (fd1g[br*32 + j]*BN_SCALE);
  } else if (r < 5120){
    int rr = r - 2048; int ci = rr >> 5, j = rr & 31;
    v = fd2w[br*3072 + j*96 + ci] * (fd2g[br*32 + j]*BN_SCALE);
  } else {
    int rr = r - 5120; int ci = rr >> 6, j = rr & 63;
    v = fcw[br*8192 + j*128 + ci];
  }
  o[i] = v;
}

// ---------- fused fd1+fd2+fconv over FFT-domain pixels (f32 exact) ----------
__global__ __launch_bounds__(256) void k_fdc(
    const float* __restrict__ in, const float* __restrict__ wT,
    const float* __restrict__ bt1, const float* __restrict__ bt2,
    float* __restrict__ outp){
  __shared__ float tls[32][64];
  __shared__ float uls[32][64];
  int b = blockIdx.x, tile = blockIdx.y;
  int tid = threadIdx.x;
  int lane = tid & 63;
  int kk = __builtin_amdgcn_readfirstlane(tid >> 6);   // wave-uniform j-group
  const float* ip = in + (size_t)b*64*HWFn + tile*64 + lane;
  {
    float t[8];
    #pragma unroll
    for (int jj=0;jj<8;jj++) t[jj] = bt1[kk*8+jj];
    for (int ci=0; ci<64; ci++){
      float v = ip[(size_t)ci*HWFn];
      const float* w = wT + ci*32 + kk*8;
      #pragma unroll
      for (int jj=0;jj<8;jj++) t[jj] = fmaf(v, w[jj], t[jj]);
    }
    #pragma unroll
    for (int jj=0;jj<8;jj++){
      float a = t[jj];
      tls[kk*8+jj][lane] = (a>=0.f)? a : 0.1f*a;
    }
  }
  __syncthreads();
  {
    float u[8];
    #pragma unroll
    for (int jj=0;jj<8;jj++) u[jj] = bt2[kk*8+jj];
    for (int ci=0; ci<64; ci++){
      float v = ip[(size_t)ci*HWFn];
      const float* w = wT + 2048 + ci*32 + kk*8;
      #pragma unroll
      for (int jj=0;jj<8;jj++) u[jj] = fmaf(v, w[jj], u[jj]);
    }
    for (int ci=0; ci<32; ci++){
      float v = tls[ci][lane];
      const float* w = wT + 2048 + (64+ci)*32 + kk*8;
      #pragma unroll
      for (int jj=0;jj<8;jj++) u[jj] = fmaf(v, w[jj], u[jj]);
    }
    #pragma unroll
    for (int jj=0;jj<8;jj++){
      float a = u[jj];
      uls[kk*8+jj][lane] = (a>=0.f)? a : 0.1f*a;
    }
  }
  __syncthreads();
  float acc[16];
  #pragma unroll
  for (int jj=0;jj<16;jj++) acc[jj] = 0.f;
  for (int ci=0; ci<64; ci++){
    float v = ip[(size_t)ci*HWFn];
    const float* w = wT + 5120 + ci*64 + kk*16;
    #pragma unroll
    for (int jj=0;jj<16;jj++) acc[jj] = fmaf(v, w[jj], acc[jj]);
  }
  for (int ci=0; ci<32; ci++){
    float v = tls[ci][lane];
    const float* w = wT + 5120 + (64+ci)*64 + kk*16;
    #pragma unroll
    for (int jj=0;jj<16;jj++) acc[jj] = fmaf(v, w[jj], acc[jj]);
  }
  for (int ci=0; ci<32; ci++){
    float v = uls[ci][lane];
    const float* w = wT + 5120 + (96+ci)*64 + kk*16;
    #pragma unroll
    for (int jj=0;jj<16;jj++) acc[jj] = fmaf(v, w[jj], acc[jj]);
  }
  float* op = outp + (size_t)b*64*HWFn + tile*64 + lane;
  #pragma unroll
  for (int jj=0;jj<16;jj++)
    op[(size_t)(kk*16+jj)*HWFn] = acc[jj];
}

// ---------- MFMA 3x3 conv: Cout=64, TWO output rows (y, y+dl) per WG ----------
// Rows y and y+dl share the 4-slab input window {y-dl, y, y+dl, y+2dl}:
// staging/output drops 3->2 rows, A-frag weight loads amortized 2x.
// Pair map: p -> g=p/dl, i=p%dl, ya=g*2*dl+i, yb=ya+dl (each row covered once).
constexpr int XST = 72;
__global__ __launch_bounds__(256) void k_mconv(
    const float* __restrict__ in, const float* __restrict__ in2,
    const unsigned short* __restrict__ wpk, const float* __restrict__ bias,
    const float* __restrict__ res, float* __restrict__ out,
    int nblk, int dl, int leaky){
  __shared__ short lds[4*134*XST];
  int b = blockIdx.x;
  int p = blockIdx.y;
  int g = p / dl, i = p - g*dl;
  int ya = g*2*dl + i;
  int tid = threadIdx.x;
  int wv = tid >> 6, lane = tid & 63;
  int nq = lane >> 4, nr = lane & 15;
  float4v acc[2][4][2];
  #pragma unroll
  for (int rr=0; rr<2; rr++)
    #pragma unroll
    for (int mt=0; mt<4; mt++)
      #pragma unroll
      for (int nt=0; nt<2; nt++) acc[rr][mt][nt] = (float4v){0.f,0.f,0.f,0.f};

  for (int blk=0; blk<nblk; blk++){
    const float* src = blk ? in2 : in;
    __syncthreads();
    // interior: 4 slabs x 16 ci-quads x 32 x-quads, packed b64 LDS writes
    for (int e = tid; e < 4*16*32; e += 256){
      int s  = e >> 9;                 // slab 0..3 -> input row ya+(s-1)*dl
      int r  = e & 511;
      int c4 = r >> 5;
      int xx = (r & 31) << 2;          // 0..124
      int yy = ya + (s-1)*dl;
      float4 v0, v1, v2, v3;
      if (yy >= 0 && yy < Hn){
        const float* sp2 = src + (((size_t)b*64 + c4*4)*Hn + yy)*Wn + xx;
        v0 = *(const float4*)(sp2);
        v1 = *(const float4*)(sp2 + HWn);
        v2 = *(const float4*)(sp2 + 2*HWn);
        v3 = *(const float4*)(sp2 + 3*HWn);
      } else {
        v0 = v1 = v2 = v3 = make_float4(0.f,0.f,0.f,0.f);
      }
      #pragma unroll
      for (int j=0; j<4; j++){
        float f0 = (&v0.x)[j], f1 = (&v1.x)[j], f2 = (&v2.x)[j], f3 = (&v3.x)[j];
        unsigned p0 = ((unsigned)(unsigned short)f2bf(f0)) | (((unsigned)(unsigned short)f2bf(f1)) << 16);
        unsigned p1 = ((unsigned)(unsigned short)f2bf(f2)) | (((unsigned)(unsigned short)f2bf(f3)) << 16);
        *(uint2*)&lds[(s*134 + xx + 3 + j)*XST + c4*4] = make_uint2(p0, p1);
      }
    }
    // edges zero: x in {0,1,2,131,132,133}, b64 per 4-ci group, all 4 slabs
    for (int e = tid; e < 4*16*6; e += 256){
      int s = e / 96; int r = e - s*96;
      int c4 = r / 6;  int k = r - c4*6;
      int x = (k < 3) ? k : 128 + k;
      *(uint2*)&lds[(s*134 + x)*XST + c4*4] = make_uint2(0u, 0u);
    }
    __syncthreads();
    const unsigned short* wb = wpk + (size_t)blk*36864;
    #pragma unroll 3
    for (int tap=0; tap<9; tap++){
      int dy = tap/3, dx = tap - (tap/3)*3;
      #pragma unroll
      for (int ks=0; ks<2; ks++){
        short8 a[4];
        #pragma unroll
        for (int mt=0; mt<4; mt++)
          a[mt] = *(const short8*)(wb + (((size_t)(tap*2+ks)*4+mt)<<9) + ((size_t)lane<<3));
        #pragma unroll
        for (int rr=0; rr<2; rr++){                  // output row ya / yb: slab dy+rr
          #pragma unroll
          for (int nt=0; nt<2; nt++){
            int x = wv*32 + nt*16 + nr + (dx-1)*dl + 3;
            short8 bf = *(const short8*)&lds[((dy+rr)*134 + x)*XST + ks*32 + nq*8];
            #pragma unroll
            for (int mt=0; mt<4; mt++)
              acc[rr][mt][nt] = __builtin_amdgcn_mfma_f32_16x16x32_bf16(a[mt], bf, acc[rr][mt][nt], 0, 0, 0);
          }
        }
      }
    }
  }
  #pragma unroll
  for (int rr=0; rr<2; rr++){
    int y = ya + rr*dl;
    if (y >= Hn) continue;                           // dl=3 tail guard
    #pragma unroll
    for (int mt=0; mt<4; mt++)
    #pragma unroll
    for (int nt=0; nt<2; nt++){
      int x = wv*32 + nt*16 + nr;
      #pragma unroll
      for (int r2=0; r2<4; r2++){
        int co = mt*16 + nq*4 + r2;
        float a = acc[rr][mt][nt][r2] + (bias ? bias[co] : 0.f);
        if (leaky) a = (a >= 0.f) ? a : 0.01f*a;
        size_t idx = (((size_t)b*64 + co)*Hn + y)*Wn + x;
        if (res) a += res[idx];
        out[idx] = a;
      }
    }
  }
}

// ---------- fused depthwise 3x3 + pointwise 1x1 (Cin=64) via MFMA ----------
template<int MT>
__global__ __launch_bounds__(256) void k_dwpw(
    const float* __restrict__ in, const float* __restrict__ dww, const float* __restrict__ dwb,
    const unsigned short* __restrict__ pwpk, const float* __restrict__ pwb,
    float* __restrict__ out, int Cout, size_t outb, int post){
  __shared__ short tb[128*72];       // dw output [x][ci] bf16
  __shared__ float wsm[640];         // dw weights 64*9 + bias 64
  int b = blockIdx.x >> 7, y = blockIdx.x & 127;
  int tid = threadIdx.x;
  for (int i = tid; i < 640; i += 256)
    wsm[i] = (i < 576) ? dww[i] : (dwb ? dwb[i-576] : 0.f);
  __syncthreads();
  for (int e = tid; e < 2048; e += 256){
    int ci = e >> 5;
    int xx = (e & 31) << 2;            // 0..124
    const float* ip = in + ((size_t)b*64 + ci)*HWn;
    const float* wp = wsm + ci*9;
    float4 a0 = make_float4(0.f,0.f,0.f,0.f), a1 = a0, a2 = a0;
    float L0=0.f,L1=0.f,L2=0.f,R0=0.f,R1=0.f,R2=0.f;
    if (y > 0){
      const float* r = ip + (y-1)*Wn;
      a0 = *(const float4*)(r + xx);
      if (xx) L0 = r[xx-1];
      if (xx < 124) R0 = r[xx+4];
    }
    {
      const float* r = ip + y*Wn;
      a1 = *(const float4*)(r + xx);
      if (xx) L1 = r[xx-1];
      if (xx < 124) R1 = r[xx+4];
    }
    if (y < Hn-1){
      const float* r = ip + (y+1)*Wn;
      a2 = *(const float4*)(r + xx);
      if (xx) L2 = r[xx-1];
      if (xx < 124) R2 = r[xx+4];
    }
    float bb = wsm[576+ci];
    float o0=bb,o1=bb,o2=bb,o3=bb;
    float w0=wp[0],w1=wp[1],w2=wp[2];
    o0 = fmaf(w0,L0,  fmaf(w1,a0.x, fmaf(w2,a0.y, o0)));
    o1 = fmaf(w0,a0.x,fmaf(w1,a0.y, fmaf(w2,a0.z, o1)));
    o2 = fmaf(w0,a0.y,fmaf(w1,a0.z, fmaf(w2,a0.w, o2)));
    o3 = fmaf(w0,a0.z,fmaf(w1,a0.w, fmaf(w2,R0,   o3)));
    w0=wp[3];w1=wp[4];w2=wp[5];
    o0 = fmaf(w0,L1,  fmaf(w1,a1.x, fmaf(w2,a1.y, o0)));
    o1 = fmaf(w0,a1.x,fmaf(w1,a1.y, fmaf(w2,a1.z, o1)));
    o2 = fmaf(w0,a1.y,fmaf(w1,a1.z, fmaf(w2,a1.w, o2)));
    o3 = fmaf(w0,a1.z,fmaf(w1,a1.w, fmaf(w2,R1,   o3)));
    w0=wp[6];w1=wp[7];w2=wp[8];
    o0 = fmaf(w0,L2,  fmaf(w1,a2.x, fmaf(w2,a2.y, o0)));
    o1 = fmaf(w0,a2.x,fmaf(w1,a2.y, fmaf(w2,a2.z, o1)));
    o2 = fmaf(w0,a2.y,fmaf(w1,a2.z, fmaf(w2,a2.w, o2)));
    o3 = fmaf(w0,a2.z,fmaf(w1,a2.w, fmaf(w2,R2,   o3)));
    short* d = &tb[xx*72 + ci];
    d[0]   = f2bf(o0);
    d[72]  = f2bf(o1);
    d[144] = f2bf(o2);
    d[216] = f2bf(o3);
  }
  __syncthreads();
  int wv = tid>>6, lane = tid&63, nq = lane>>4, nr = lane&15;
  float4v acc[MT][2];
  #pragma unroll
  for (int mt=0; mt<MT; mt++)
    #pragma unroll
    for (int nt=0; nt<2; nt++) acc[mt][nt] = (float4v){0.f,0.f,0.f,0.f};
  #pragma unroll
  for (int ks=0; ks<2; ks++){
    short8 a[MT];
    #pragma unroll
    for (int mt=0; mt<MT; mt++)
      a[mt] = *(const short8*)(pwpk + ((ks*MT+mt)<<9) + (lane<<3));
    #pragma unroll
    for (int nt=0; nt<2; nt++){
      int x = wv*32 + nt*16 + nr;
      short8 bf = *(const short8*)&tb[x*72 + ks*32 + nq*8];
      #pragma unroll
      for (int mt=0; mt<MT; mt++)
        acc[mt][nt] = __builtin_amdgcn_mfma_f32_16x16x32_bf16(a[mt], bf, acc[mt][nt], 0, 0, 0);
    }
  }
  #pragma unroll
  for (int mt=0; mt<MT; mt++)
  #pragma unroll
  for (int nt=0; nt<2; nt++){
    int x = wv*32 + nt*16 + nr;
    #pragma unroll
    for (int r2=0; r2<4; r2++){
      int co = mt*16 + nq*4 + r2;
      if (co < Cout){
        float a = acc[mt][nt][r2] + (pwb ? pwb[co] : 0.f);
        if (post == 1) a = fminf(fmaxf(a, -1.f), 1.f);
        else if (post == 2) a = a*fminf(fmaxf(a+3.f, 0.f), 6.f)*(1.f/6.f);
        out[(size_t)b*outb + (size_t)co*HWn + y*Wn + x] = a;
      }
    }
  }
}

// ---------- fused deformable dw 3x3 + pointwise 1x1 (64 -> Cout<=16) ----------
__global__ __launch_bounds__(512) void k_defpw(
    const float* __restrict__ xg, const float* __restrict__ off, const float* __restrict__ dcnw,
    const unsigned short* __restrict__ pwpk, float* __restrict__ out,
    int Cout, size_t outb, int post){
  __shared__ unsigned short xs[5*64*130];   // [tr][ci][c] bf16 (83.2 KB)
  __shared__ short tb[128*72];
  __shared__ float wsm[576];
  int b = blockIdx.x >> 7, y = blockIdx.x & 127;
  int tid = threadIdx.x;
  int px = tid & 127, sub = tid >> 7;       // 4 threads per pixel
  for (int i = tid; i < 576; i += 512) wsm[i] = dcnw[i];
  for (int e = tid; e < 10240; e += 512){   // 5*64*32 float4 units
    int tr = e >> 11;
    int r  = e & 2047;
    int ci = r >> 5;
    int xx = (r & 31) << 2;
    int gy = min(max(y - 2 + tr, 0), Hn-1);
    float4 v = *(const float4*)&xg[(((size_t)b*64 + ci)*Hn + gy)*Wn + xx];
    unsigned short* d = &xs[(tr*64 + ci)*130 + xx];
    d[0] = (unsigned short)f2bf(v.x);
    d[1] = (unsigned short)f2bf(v.y);
    d[2] = (unsigned short)f2bf(v.z);
    d[3] = (unsigned short)f2bf(v.w);
  }
  const float* op = off + (size_t)b*18*HWn + y*Wn + px;
  int t0[9], t1[9], c0[9], c1[9];
  float w00[9], w01[9], w10[9], w11[9];
  #pragma unroll
  for (int k=0; k<9; k++){
    int ky = k/3 - 1, kx = k - (k/3)*3 - 1;
    float oy = op[(size_t)(2*k)*HWn];
    float ox = op[(size_t)(2*k+1)*HWn];
    float py = (float)(y + ky) + oy;
    float pxx = (float)(px + kx) + ox;
    float fy = floorf(py), fx = floorf(pxx);
    float wy = py - fy, wx = pxx - fx;
    int y0 = (int)fy, x0 = (int)fx;
    float vy0 = (y0 >= 0 && y0 < Hn) ? 1.f : 0.f;
    float vy1 = (y0+1 >= 0 && y0+1 < Hn) ? 1.f : 0.f;
    float vx0 = (x0 >= 0 && x0 < Wn) ? 1.f : 0.f;
    float vx1 = (x0+1 >= 0 && x0+1 < Wn) ? 1.f : 0.f;
    w00[k] = (1.f-wy)*(1.f-wx)*vy0*vx0;
    w01[k] = (1.f-wy)*wx*vy0*vx1;
    w10[k] = wy*(1.f-wx)*vy1*vx0;
    w11[k] = wy*wx*vy1*vx1;
    t0[k] = min(max(min(max(y0,   0), Hn-1) - (y-2), 0), 4);
    t1[k] = min(max(min(max(y0+1, 0), Hn-1) - (y-2), 0), 4);
    c0[k] = min(max(x0,   0), Wn-1);
    c1[k] = min(max(x0+1, 0), Wn-1);
  }
  __syncthreads();
  for (int ci = sub; ci < 64; ci += 4){
    float acc = 0.f;
    #pragma unroll
    for (int k=0; k<9; k++){
      const unsigned short* b0 = &xs[(t0[k]*64 + ci)*130];
      const unsigned short* b1 = &xs[(t1[k]*64 + ci)*130];
      float v = w00[k]*bf2f(b0[c0[k]]) + w01[k]*bf2f(b0[c1[k]])
              + w10[k]*bf2f(b1[c0[k]]) + w11[k]*bf2f(b1[c1[k]]);
      acc = fmaf(v, wsm[ci*9 + k], acc);
    }
    tb[px*72 + ci] = f2bf(acc);
  }
  __syncthreads();
  int wv = tid>>6, lane = tid&63, nq = lane>>4, nr = lane&15;
  float4v acc = (float4v){0.f,0.f,0.f,0.f};
  int x = wv*16 + nr;
  #pragma unroll
  for (int ks=0; ks<2; ks++){
    short8 a = *(const short8*)(pwpk + (ks<<9) + (lane<<3));
    short8 bf = *(const short8*)&tb[x*72 + ks*32 + nq*8];
    acc = __builtin_amdgcn_mfma_f32_16x16x32_bf16(a, bf, acc, 0, 0, 0);
  }
  #pragma unroll
  for (int r2=0; r2<4; r2++){
    int co = nq*4 + r2;
    if (co < Cout){
      float a = acc[r2];
      if (post == 2) a = a*fminf(fmaxf(a+3.f, 0.f), 6.f)*(1.f/6.f);
      out[(size_t)b*outb + (size_t)co*HWn + y*Wn + x] = a;
    }
  }
}

// ---------- depthwise 3x3, pad 1 (phase-1, 3ch) ----------
__global__ void k_dw3x3(const float* __restrict__ in, const float* __restrict__ w,
                        const float* __restrict__ bias, float* __restrict__ out, int C){
  int bc = blockIdx.x; int y = blockIdx.y; int x = threadIdx.x;
  int c = bc % C;
  const float* ip = in + (size_t)bc*HWn;
  const float* wp = w + c*9;
  float acc = bias ? bias[c] : 0.f;
  #pragma unroll
  for (int ky=0; ky<3; ky++){
    int yy = y + ky - 1; if (yy < 0 || yy >= Hn) continue;
    #pragma unroll
    for (int kx=0; kx<3; kx++){
      int xx = x + kx - 1; if (xx < 0 || xx >= Wn) continue;
      acc = fmaf(ip[yy*Wn+xx], wp[ky*3+kx], acc);
    }
  }
  out[(size_t)bc*HWn + y*Wn + x] = acc;
}

// ---------- pointwise 1x1, register-tiled (phase-1 only) ----------
template<int CT>
__global__ void k_pwt(const float* __restrict__ in, const float* __restrict__ wg,
                      const float* __restrict__ bias, const float* __restrict__ bng,
                      const float* __restrict__ bnb, float* __restrict__ out,
                      int Cin, int Cout, int npix, int inb, int outb, int post, float slope){
  extern __shared__ float wsm[];
  int nt = (Cout + CT - 1)/CT;
  int b = blockIdx.x / nt, t = blockIdx.x - b*nt;
  int co0 = t*CT;
  for (int i = threadIdx.x; i < CT*Cin; i += 256){
    int co = i / Cin;
    wsm[i] = (co0 + co < Cout) ? wg[(size_t)(co0+co)*Cin + (i - co*Cin)] : 0.f;
  }
  __syncthreads();
  int p = blockIdx.y*256 + threadIdx.x;
  if (p >= npix) return;
  const float* ip = in + (size_t)b*inb + p;
  float acc[CT];
  #pragma unroll
  for (int j=0; j<CT; j++) acc[j] = 0.f;
  for (int ci=0; ci<Cin; ci++){
    float v = ip[(size_t)ci*npix];
    #pragma unroll
    for (int j=0; j<CT; j++) acc[j] = fmaf(v, wsm[j*Cin+ci], acc[j]);
  }
  #pragma unroll
  for (int j=0; j<CT; j++){
    int co = co0 + j;
    if (co < Cout){
      float a = acc[j] + (bias ? bias[co] : 0.f);
      if (bng) a = a*(bng[co]*BN_SCALE) + bnb[co];
      if (post == 1) a = fminf(fmaxf(a, -1.f), 1.f);
      else if (post == 2) a = a*fminf(fmaxf(a+3.f, 0.f), 6.f)*(1.f/6.f);
      else if (post == 3) a = (a >= 0.f) ? a : a*slope;
      out[(size_t)b*outb + (size_t)co*npix + p] = a;
    }
  }
}

// ---------- deformable depthwise 3x3 (phase-1, 3ch) ----------
__global__ void k_deform(const float* __restrict__ x, const float* __restrict__ off,
                         const float* __restrict__ w, float* __restrict__ out, int C){
  int bc = blockIdx.x; int b = bc / C; int c = bc - b*C;
  int y = blockIdx.y; int x0 = threadIdx.x;
  const float* xp = x + (size_t)bc*HWn;
  const float* op = off + (size_t)b*18*HWn + y*Wn + x0;
  const float* wp = w + c*9;
  float acc = 0.f;
  #pragma unroll
  for (int k=0; k<9; k++){
    int ky = k/3 - 1, kx = k - (k/3)*3 - 1;
    float oy = op[(size_t)(2*k)*HWn];
    float ox = op[(size_t)(2*k+1)*HWn];
    float py = (float)y + (float)ky + oy;
    float px = (float)x0 + (float)kx + ox;
    float fy = floorf(py), fx = floorf(px);
    float wy = py - fy, wx = px - fx;
    int y0 = (int)fy, xx0 = (int)fx;
    float val = 0.f;
    #pragma unroll
    for (int dy=0; dy<2; dy++){
      int iy = y0 + dy; if (iy < 0 || iy >= Hn) continue;
      float wyv = dy ? wy : (1.f - wy);
      #pragma unroll
      for (int dx=0; dx<2; dx++){
        int ix = xx0 + dx; if (ix < 0 || ix >= Wn) continue;
        float wxv = dx ? wx : (1.f - wx);
        val = fmaf(xp[iy*Wn+ix], wyv*wxv, val);
      }
    }
    acc = fmaf(val, wp[k], acc);
  }
  out[(size_t)bc*HWn + y*Wn + x0] = acc;
}

// ---------- small direct conv (final 6->3) ----------
__global__ void k_conv3x3s(const float* __restrict__ in, const float* __restrict__ wgt,
                           const float* __restrict__ bias, const float* __restrict__ res,
                           float* __restrict__ out, int Cin, int Cout){
  int g = blockIdx.x;
  int b = g / Cout; int o0 = g - b*Cout;
  int y = blockIdx.y, x = threadIdx.x;
  float acc = bias ? bias[o0] : 0.f;
  for (int ci=0; ci<Cin; ci++){
    const float* iip = in + ((size_t)b*Cin + ci)*HWn;
    const float* wp = wgt + ((size_t)o0*Cin + ci)*9;
    #pragma unroll
    for (int ky=0; ky<3; ky++){
      int yy = y + ky - 1; if (yy < 0 || yy >= Hn) continue;
      #pragma unroll
      for (int kx=0; kx<3; kx++){
        int xx = x + kx - 1; if (xx < 0 || xx >= Wn) continue;
        acc = fmaf(iip[yy*Wn+xx], wp[ky*3+kx], acc);
      }
    }
  }
  size_t idx = ((size_t)b*Cout + o0)*HWn + y*Wn + x;
  if (res) acc += res[idx];
  out[idx] = acc;
}

// ---------- fused cross-attention: one WG per (b,h) ----------
__global__ __launch_bounds__(256) void k_attn(
    const float* __restrict__ q, const float* __restrict__ k,
    const float* __restrict__ v, float* __restrict__ o){
  __shared__ float qs[64][129];
  __shared__ float ks[64][129];
  __shared__ float vs[64][129];
  __shared__ float ps[64][66];
  int bh = blockIdx.x; int b = bh >> 7, h = bh & 127;
  size_t base = ((size_t)b*64*128 + h)*128;
  int tid = threadIdx.x;
  for (int e = tid; e < 8192; e += 256){
    int c = e >> 7, w = e & 127;
    size_t g = base + (size_t)c*HWn + w;
    qs[c][w] = q[g]; ks[c][w] = k[g]; vs[c][w] = v[g];
  }
  __syncthreads();
  {
    int c0 = (tid >> 4) << 2, d0 = (tid & 15) << 2;
    float acc[4][4];
    #pragma unroll
    for (int a=0; a<4; a++)
      #pragma unroll
      for (int bb=0; bb<4; bb++) acc[a][bb] = 0.f;
    for (int i=0; i<128; i++){
      float qv[4], kv[4];
      #pragma unroll
      for (int a=0; a<4; a++){ qv[a] = qs[c0+a][i]; kv[a] = ks[d0+a][i]; }
      #pragma unroll
      for (int a=0; a<4; a++)
        #pragma unroll
        for (int bb=0; bb<4; bb++) acc[a][bb] = fmaf(qv[a], kv[bb], acc[a][bb]);
    }
    #pragma unroll
    for (int a=0; a<4; a++)
      #pragma unroll
      for (int bb=0; bb<4; bb++)
        ps[c0+a][d0+bb] = acc[a][bb] * 0.35355339059327373f;
  }
  __syncthreads();
  {
    int wv = tid >> 6, lane = tid & 63;
    for (int it=0; it<16; it++){
      int row = wv*16 + it;
      float vv = ps[row][lane];
      float m = vv;
      #pragma unroll
      for (int off=32; off; off>>=1) m = fmaxf(m, __shfl_xor(m, off));
      float e = expf(vv - m);
      float s = e;
      #pragma unroll
      for (int off=32; off; off>>=1) s += __shfl_xor(s, off);
      ps[row][lane] = e / s;
    }
  }
  __syncthreads();
  {
    int c0 = (tid >> 4) << 2, w0 = (tid & 15) << 3;
    float acc[4][8];
    #pragma unroll
    for (int a=0; a<4; a++)
      #pragma unroll
      for (int j=0; j<8; j++) acc[a][j] = 0.f;
    for (int d=0; d<64; d++){
      float pv[4], vv[8];
      #pragma unroll
      for (int a=0; a<4; a++) pv[a] = ps[c0+a][d];
      #pragma unroll
      for (int j=0; j<8; j++) vv[j] = vs[d][w0+j];
      #pragma unroll
      for (int a=0; a<4; a++)
        #pragma unroll
        for (int j=0; j<8; j++) acc[a][j] = fmaf(pv[a], vv[j], acc[a][j]);
    }
    #pragma unroll
    for (int a=0; a<4; a++)
      #pragma unroll
      for (int j=0; j<8; j++)
        o[base + (size_t)(c0+a)*HWn + w0 + j] = acc[a][j];
  }
}

// ============ wave-level 128-pt FFT (no barriers, register-resident) ============
__device__ __forceinline__ float2 cmul(float2 a, float2 b){
  return make_float2(a.x*b.x - a.y*b.y, a.x*b.y + a.y*b.x);
}

// two interleaved 128-pt FFTs: (z[0],z[1]) and (z[2],z[3]) — 4 chains in flight
__device__ __forceinline__ void wfft4(float2* z, const float2* twl, int l){
  #pragma unroll
  for (int q=0; q<2; q++){
    float dx = z[2*q].x - z[2*q+1].x, dy = z[2*q].y - z[2*q+1].y;
    z[2*q].x += z[2*q+1].x; z[2*q].y += z[2*q+1].y;
    z[2*q+1] = cmul(make_float2(dx, dy), twl[6]);
  }
  #pragma unroll
  for (int s = 5; s >= 0; --s){
    int h = 1 << s;
    bool up = (l & h) != 0;
    float2 w = twl[s];
    #pragma unroll
    for (int q=0; q<4; q++){
      float ox = __shfl_xor(z[q].x, h), oy = __shfl_xor(z[q].y, h);
      float sx = up ? ox - z[q].x : z[q].x + ox;
      float sy = up ? oy - z[q].y : z[q].y + oy;
      float2 t = cmul(make_float2(sx, sy), w);
      z[q].x = up ? t.x : sx;  z[q].y = up ? t.y : sy;
    }
  }
}

__device__ __forceinline__ void wreorder(float2 z0, float2 z1, float2& n0, float2& n1, int l){
  int a = (int)(__brev((unsigned)(l >> 1)) >> 26);
  float p0x = __shfl(z0.x, a),   p0y = __shfl(z0.y, a);
  float p1x = __shfl(z1.x, a),   p1y = __shfl(z1.y, a);
  float q0x = __shfl(z0.x, a+1), q0y = __shfl(z0.y, a+1);
  float q1x = __shfl(z1.x, a+1), q1y = __shfl(z1.y, a+1);
  bool odd = (l & 1) != 0;
  n0 = odd ? make_float2(p1x, p1y) : make_float2(p0x, p0y);
  n1 = odd ? make_float2(q1x, q1y) : make_float2(q0x, q0y);
}

// ---------- fused rfft2 + mag/pha: 512 threads (8 waves) for TLP ----------
__global__ __launch_bounds__(512) void k_fft2(
    const float* __restrict__ x, float* __restrict__ mag, float* __restrict__ pha){
  __shared__ float spr[8320];
  __shared__ float spi[8320];
  int img = blockIdx.x;
  int tid = threadIdx.x;
  int wv = tid >> 6, l = tid & 63;
  float2 twl[7];
  #pragma unroll
  for (int s = 0; s < 7; ++s){
    int jh = (l & ((1 << s) - 1)) << (6 - s);
    float sv, cv; sincosf(-TWOPI * (float)jh * (1.f/128.f), &sv, &cv);
    twl[s] = make_float2(cv, sv);
  }
  const float* xp = x + (size_t)img*HWn;
  // row FFTs: two packed-row FFTs per iteration (f and f+32)
  for (int f = wv; f < 32; f += 8){
    int fB = f + 32;
    float2 z[4];
    {
      const float* a0 = xp + (2*f)*Wn;  const float* a1 = a0 + Wn;
      const float* b0 = xp + (2*fB)*Wn; const float* b1 = b0 + Wn;
      z[0] = make_float2(a0[l],      a1[l]);
      z[1] = make_float2(a0[64 + l], a1[64 + l]);
      z[2] = make_float2(b0[l],      b1[l]);
      z[3] = make_float2(b0[64 + l], b1[64 + l]);
    }
    wfft4(z, twl, l);
    #pragma unroll
    for (int q=0; q<2; q++){
      int ff = q ? fB : f;
      float2 n0, n1; wreorder(z[2*q], z[2*q+1], n0, n1, l);
      float zhx = __shfl(n1.x, (64 - l) & 63);
      float zhy = __shfl(n1.y, (64 - l) & 63);
      float2 Zn = (l == 0) ? n0 : make_float2(zhx, zhy);
      int iA = (2*ff)*65 + l, iB = (2*ff+1)*65 + l;
      spr[iA] = 0.5f*(n0.x + Zn.x);  spi[iA] = 0.5f*(n0.y - Zn.y);
      spr[iB] = 0.5f*(n0.y + Zn.y);  spi[iB] = 0.5f*(Zn.x - n0.x);
      if (l == 0){
        spr[(2*ff)*65 + 64]   = n1.x;  spi[(2*ff)*65 + 64]   = 0.f;
        spr[(2*ff+1)*65 + 64] = n1.y;  spi[(2*ff+1)*65 + 64] = 0.f;
      }
    }
  }
  __syncthreads();
  // column FFTs: pairs (c, c+33); partner invalid only for c=32
  for (int c = wv; c < 33; c += 8){
    int cB = c + 33;
    bool h2 = cB < 65;
    int cB_s = h2 ? cB : c;
    float2 z[4];
    z[0] = make_float2(spr[l*65 + c],        spi[l*65 + c]);
    z[1] = make_float2(spr[(64 + l)*65 + c], spi[(64 + l)*65 + c]);
    z[2] = make_float2(spr[l*65 + cB_s],        spi[l*65 + cB_s]);
    z[3] = make_float2(spr[(64 + l)*65 + cB_s], spi[(64 + l)*65 + cB_s]);
    wfft4(z, twl, l);
    {
      float2 n0, n1; wreorder(z[0], z[1], n0, n1, l);
      spr[l*65 + c]        = sqrtf(n0.x*n0.x + n0.y*n0.y);
      spi[l*65 + c]        = atan2f(n0.y, n0.x);
      spr[(64 + l)*65 + c] = sqrtf(n1.x*n1.x + n1.y*n1.y);
      spi[(64 + l)*65 + c] = atan2f(n1.y, n1.x);
    }
    if (h2){
      float2 n0, n1; wreorder(z[2], z[3], n0, n1, l);
      spr[l*65 + cB]        = sqrtf(n0.x*n0.x + n0.y*n0.y);
      spi[l*65 + cB]        = atan2f(n0.y, n0.x);
      spr[(64 + l)*65 + cB] = sqrtf(n1.x*n1.x + n1.y*n1.y);
      spi[(64 + l)*65 + cB] = atan2f(n1.y, n1.x);
    }
  }
  __syncthreads();
  float* mp = mag + (size_t)img*HWFn;
  float* pp = pha + (size_t)img*HWFn;
  for (int i = tid; i < 8320; i += 512){
    mp[i] = spr[i]; pp[i] = spi[i];
  }
}

// ---------- fused irfft2 + residual add: 512 threads ----------
__global__ __launch_bounds__(512) void k_ifft2(
    const float* __restrict__ mo, const float* __restrict__ po,
    const float* __restrict__ hsrc, float* __restrict__ outp){
  __shared__ float spr[8320];
  __shared__ float spi[8320];
  int img = blockIdx.x;
  int tid = threadIdx.x;
  int wv = tid >> 6, l = tid & 63;
  float2 twl[7];
  #pragma unroll
  for (int s = 0; s < 7; ++s){
    int jh = (l & ((1 << s) - 1)) << (6 - s);
    float sv, cv; sincosf(TWOPI * (float)jh * (1.f/128.f), &sv, &cv);
    twl[s] = make_float2(cv, sv);
  }
  const float* mp = mo + (size_t)img*HWFn;
  const float* pp = po + (size_t)img*HWFn;
  for (int i = tid; i < 8320; i += 512){
    float m = mp[i], p = pp[i];
    float sv, cv; sincosf(p, &sv, &cv);
    spr[i] = m*cv; spi[i] = m*sv;
  }
  __syncthreads();
  // column inverse: pairs (c, c+33)
  for (int c = wv; c < 33; c += 8){
    int cB = c + 33;
    bool h2 = cB < 65;
    int cB_s = h2 ? cB : c;
    float2 z[4];
    z[0] = make_float2(spr[l*65 + c],        spi[l*65 + c]);
    z[1] = make_float2(spr[(64 + l)*65 + c], spi[(64 + l)*65 + c]);
    z[2] = make_float2(spr[l*65 + cB_s],        spi[l*65 + cB_s]);
    z[3] = make_float2(spr[(64 + l)*65 + cB_s], spi[(64 + l)*65 + cB_s]);
    wfft4(z, twl, l);
    {
      float2 n0, n1; wreorder(z[0], z[1], n0, n1, l);
      spr[l*65 + c] = n0.x;        spi[l*65 + c] = n0.y;
      spr[(64 + l)*65 + c] = n1.x; spi[(64 + l)*65 + c] = n1.y;
    }
    if (h2){
      float2 n0, n1; wreorder(z[2], z[3], n0, n1, l);
      spr[l*65 + cB] = n0.x;        spi[l*65 + cB] = n0.y;
      spr[(64 + l)*65 + cB] = n1.x; spi[(64 + l)*65 + cB] = n1.y;
    }
  }
  __syncthreads();
  const float scl = 1.f/16384.f;
  // row inverse c2r: pairs (f, f+32)
  for (int f = wv; f < 32; f += 8){
    int fB = f + 32;
    float2 z[4];
    #pragma unroll
    for (int q=0; q<2; q++){
      int ff = q ? fB : f;
      int iA = (2*ff)*65 + l, iB = (2*ff+1)*65 + l;
      float2 A  = make_float2(spr[iA], spi[iA]);
      float2 Bv = make_float2(spr[iB], spi[iB]);
      if (l == 0){ A.y = 0.f; Bv.y = 0.f; }
      z[2*q] = make_float2(A.x - Bv.y, A.y + Bv.x);
      int lm = 64 - l;
      float2 Am = make_float2(spr[(2*ff)*65 + lm],   spi[(2*ff)*65 + lm]);
      float2 Bm = make_float2(spr[(2*ff+1)*65 + lm], spi[(2*ff+1)*65 + lm]);
      z[2*q+1] = (l == 0) ? make_float2(Am.x, Bm.x)
                          : make_float2(Am.x + Bm.y, Bm.x - Am.y);
    }
    wfft4(z, twl, l);
    #pragma unroll
    for (int q=0; q<2; q++){
      int ff = q ? fB : f;
      float2 n0, n1; wreorder(z[2*q], z[2*q+1], n0, n1, l);
      size_t g0 = (size_t)img*HWn + (size_t)(2*ff)*Wn + l;
      size_t g1 = g0 + Wn;
      outp[g0]      = n0.x*scl + hsrc[g0];
      outp[g0 + 64] = n1.x*scl + hsrc[g0 + 64];
      outp[g1]      = n0.y*scl + hsrc[g1];
      outp[g1 + 64] = n1.y*scl + hsrc[g1 + 64];
    }
  }
}

} // namespace

extern "C" void kernel_launch(void* const* d_in, const int* in_sizes, int n_in,
                              void* d_out, int out_size, void* d_ws, size_t ws_size,
                              hipStream_t stream){
  const float *xf   =(const float*)d_in[0],  *chodw=(const float*)d_in[1],
              *chopw=(const float*)d_in[2],  *chdcn=(const float*)d_in[3],
              *chpw =(const float*)d_in[4],  *ctodw=(const float*)d_in[5],
              *ctopw=(const float*)d_in[6],  *ctdcn=(const float*)d_in[7],
              *ctpw =(const float*)d_in[8],  *dbw  =(const float*)d_in[9],
              *dbb  =(const float*)d_in[10], *cadw =(const float*)d_in[11],
              *cadb =(const float*)d_in[12], *capw =(const float*)d_in[13],
              *capb =(const float*)d_in[14], *hhw  =(const float*)d_in[15],
              *hhb  =(const float*)d_in[16], *fd1w =(const float*)d_in[17],
              *fd2w =(const float*)d_in[18], *fd1g =(const float*)d_in[19],
              *fd1bt=(const float*)d_in[20], *fd2g =(const float*)d_in[21],
              *fd2bt=(const float*)d_in[22], *fcw  =(const float*)d_in[23],
              *cw   =(const float*)d_in[24], *cb   =(const float*)d_in[25];

  constexpr size_t M = 1048576;            // one batch x 64ch x HW (floats)
  float* ws = (float*)d_ws;
  float* h     = ws;                       // 12*M
  float* fftHL = ws + 12*M;                // 4*M
  float* cat6  = ws + 16*M;                // 1,179,648
  unsigned short* wpkDB = (unsigned short*)(cat6 + 1179648);
  unsigned short* wpkHH = wpkDB + 552960;
  float* wfdc = (float*)(wpkHH + 73728);   // 26624 floats (2 branches x 13312)
  float* P = cat6 + 1179648 + 313344 + 26624;   // pool

  const int NB = (ws_size >= 266018816ull) ? 4 : 1;
  const size_t S = (size_t)NB*M;
  float* kb  = P;        float* vb  = P + S;   float* qb  = P + 2*S;
  float* qsl = P + 3*S;  // packed pw weights live here (written after phase 2)
  float* aA  = P + 4*S;  float* aB  = P + 5*S;
  float* aC  = P + 6*S;  float* hh1 = P + 7*S; float* sA  = P + 8*S;
  float* sB  = P + 9*S;  float* dbuf= P + 10*S;
  float* X   = P + 11*S;
  unsigned short* pwpkCA = (unsigned short*)qsl;      // 6*4096
  unsigned short* pwpkTO = pwpkCA + 24576;            // 2048
  unsigned short* pwpkTP = pwpkTO + 2048;             // 1024
  // phase-1 aliases
  float* dwb3 = P; float* offb12 = P + 589824; float* yb3 = P + 4128768;

  float* out = (float*)d_out;
  float* out0 = out;
  float* out1 = out + 589824;
  float* out2 = out + 589824 + 6389760;

  auto PW = [&](const float* in, const float* wg, const float* bi, const float* g, const float* bt,
                float* o, int B, int Ci, int Co, int npix, int inb, int outb, int post, float slope){
    int py = (npix + 255)/256;
    if (Co > 32){
      k_pwt<32><<<dim3(B*2, py), 256, 32*Ci*4, stream>>>(in, wg, bi, g, bt, o, Ci, Co, npix, inb, outb, post, slope);
    } else if (Co > 18){
      k_pwt<32><<<dim3(B, py), 256, 32*Ci*4, stream>>>(in, wg, bi, g, bt, o, Ci, Co, npix, inb, outb, post, slope);
    } else if (Co > 3){
      k_pwt<18><<<dim3(B, py), 256, 18*Ci*4, stream>>>(in, wg, bi, g, bt, o, Ci, Co, npix, inb, outb, post, slope);
    } else {
      k_pwt<3><<<dim3(B, py), 256, 3*Ci*4, stream>>>(in, wg, bi, g, bt, o, Ci, Co, npix, inb, outb, post, slope);
    }
  };
  auto MCONV = [&](const float* in, const float* in2, const unsigned short* wp, const float* bi,
                   const float* res, float* o, int B, int nblk, int dl, int lk){
    int npairs = (dl == 3) ? 66 : 64;
    k_mconv<<<dim3(B, npairs), 256, 0, stream>>>(in, in2, wp, bi, res, o, nblk, dl, lk);
  };
  auto DILm = [&](const float* in, int set, const float* bset, int B){
    const unsigned short* w5 = wpkDB + (size_t)set*5*36864;
    MCONV(in, nullptr, w5,          bset,      nullptr, sA,   B, 1, 1, 1);
    MCONV(sA, nullptr, w5+36864,    bset+64,   nullptr, sB,   B, 1, 2, 1);
    MCONV(sB, nullptr, w5+2*36864,  bset+128,  nullptr, sA,   B, 1, 3, 1);
    MCONV(sA, nullptr, w5+3*36864,  bset+192,  nullptr, sB,   B, 1, 2, 1);
    MCONV(sB, nullptr, w5+4*36864,  bset+256,  in,      dbuf, B, 1, 1, 0);
  };
  auto DCONVm = [&](const float* in, int idx, float* o, int B){
    k_dwpw<4><<<B*128, 256, 0, stream>>>(in, cadw + idx*576, cadb + idx*64,
        pwpkCA + (size_t)idx*4096, capb + idx*64, o, 64, (size_t)64*HWn, 0);
  };
  auto ATTNm = [&](const float* qsrc, int qidx, float* o, int B){
    DCONVm(qsrc, qidx, qb, B);
    k_attn<<<B*128, 256, 0, stream>>>(qb, kb, vb, o);
  };
  auto PEMBEDm = [&](const float* in, float* outSlice, int B){
    k_dwpw<2><<<B*128, 256, 0, stream>>>(in, ctodw, nullptr, pwpkTO, nullptr,
        X, 18, (size_t)18*HWn, 1);
    k_defpw<<<B*128, 512, 0, stream>>>(in, X, ctdcn, pwpkTP, outSlice, 3, (size_t)6*HWn, 2);
  };

  // ===== Pack 3x3 conv weights + fdc weight transform =====
  k_pack<<<(552960 + 255)/256, 256, 0, stream>>>(dbw, wpkDB, 64, 36864, 552960);
  k_pack<<<288, 256, 0, stream>>>(hhw, wpkHH, 128, 73728, 73728);
  k_wfdc<<<104, 256, 0, stream>>>(fd1w, fd2w, fcw, fd1g, fd2g, wfdc);

  // ===== Phase 1: patch_embed(ch) -> h (3-channel, unfused path) =====
  k_dw3x3<<<dim3(36, Hn), 128, 0, stream>>>(xf, chodw, nullptr, dwb3, 3);
  PW(dwb3, chopw, nullptr, nullptr, nullptr, offb12, 12, 3, 18, HWn, 3*HWn, 18*HWn, 1, 0.f);
  k_deform<<<dim3(36, Hn), 128, 0, stream>>>(xf, offb12, chdcn, yb3, 3);
  PW(yb3, chpw, nullptr, nullptr, nullptr, h, 12, 3, 64, HWn, 3*HWn, 64*HWn, 2, 0.f);

  // ===== Phase 2: fft_block (wave-register 2-D FFT + fused branch chain) =====
  if (NB == 4){
    float* mB = P;                 // [12][64][8320]
    float* pB = P + 6389760;
    k_fft2<<<768, 512, 0, stream>>>(h, mB, pB);
    k_fdc<<<dim3(12, 130), 256, 0, stream>>>(mB, wfdc,         fd1bt,      fd2bt,      out1);
    k_fdc<<<dim3(12, 130), 256, 0, stream>>>(pB, wfdc + 13312, fd1bt + 32, fd2bt + 32, out2);
    k_ifft2<<<256, 512, 0, stream>>>(out1, out2, h, fftHL);
  } else {
    // 3 chunks of 4 batches
    float* mB = P;                 // [4][64][8320]
    float* pB = P + 2129920;
    for (int c=0; c<3; c++){
      const float* hsrc = h + (size_t)c*4*M;
      float* o1 = out1 + (size_t)c*2129920;
      float* o2 = out2 + (size_t)c*2129920;
      k_fft2<<<256, 512, 0, stream>>>(hsrc, mB, pB);
      k_fdc<<<dim3(4, 130), 256, 0, stream>>>(mB, wfdc,         fd1bt,      fd2bt,      o1);
      k_fdc<<<dim3(4, 130), 256, 0, stream>>>(pB, wfdc + 13312, fd1bt + 32, fd2bt + 32, o2);
      if (c == 0)
        k_ifft2<<<256, 512, 0, stream>>>(out1, out2, h, fftHL);
    }
  }

  // ===== Pack 1x1 pw weights (into pool slot; free after phase 2) =====
  k_packpw<<<96, 256, 0, stream>>>(capw,  pwpkCA, 64, 4, 24576);
  k_packpw<<<8,  256, 0, stream>>>(ctopw, pwpkTO, 18, 2, 2048);
  k_packpw<<<4,  256, 0, stream>>>(ctpw,  pwpkTP, 3,  1, 1024);

  // ===== Phases 3-5 in groups of NB batches =====
  for (int g0=0; g0<4; g0+=NB){
    const float* hHL = h + (size_t)g0*M;
    const float* hLH = h + (size_t)(4+g0)*M;
    const float* hHH = h + (size_t)(8+g0)*M;
    const float* fHL = fftHL + (size_t)g0*M;
    DCONVm(hHH, 1, kb, NB);
    DCONVm(hHH, 2, vb, NB);
    ATTNm(hLH, 0, aA, NB);                       // x_HH_LH (== f_HH_LH)
    DCONVm(hHH, 4, kb, NB);
    DCONVm(hHH, 5, vb, NB);
    ATTNm(hHL, 3, aB, NB);                       // x_HH_HL
    ATTNm(fHL, 3, aC, NB);                       // f_HH_HL
    // x_HH2 path
    MCONV(aA, aB, wpkHH, hhb, nullptr, hh1, NB, 2, 1, 0);
    DILm(hh1, 2, dbb + 2*320, NB);
    PEMBEDm(dbuf, cat6 + (size_t)((8+g0)*6)*HWn, NB);
    // f_HH2 path
    MCONV(aA, aC, wpkHH, hhb, nullptr, hh1, NB, 2, 1, 0);
    DILm(hh1, 2, dbb + 2*320, NB);
    PEMBEDm(dbuf, cat6 + (size_t)((8+g0)*6+3)*HWn, NB);
    // x_HL2 / x_LH2
    DILm(hHL, 1, dbb + 320, NB);
    PEMBEDm(dbuf, cat6 + (size_t)(g0*6)*HWn, NB);
    DILm(hLH, 0, dbb, NB);
    PEMBEDm(dbuf, cat6 + (size_t)((4+g0)*6)*HWn, NB);
    // fft_HL / fft_LH passthroughs
    PEMBEDm(fHL, cat6 + (size_t)(g0*6+3)*HWn, NB);
    PEMBEDm(hLH, cat6 + (size_t)((4+g0)*6+3)*HWn, NB);
  }

  // ===== Final conv + residual -> out0 =====
  k_conv3x3s<<<dim3(36, Hn), 128, 0, stream>>>(cat6, cw, cb, xf, out0, 6, 3);
}

// Round 11
// 1648.152 us; speedup vs baseline: 1.0161x; 1.0161x over previous
//
#include <hip/hip_runtime.h>

namespace {

constexpr int Hn = 128, Wn = 128, HWn = 16384, HWFn = 8320;
constexpr float TWOPI = 6.2831853071795864769f;
constexpr float BN_SCALE = 0.99999500003749968f;   // 1/sqrt(1+1e-5)

typedef __attribute__((ext_vector_type(8))) short short8;
typedef __attribute__((ext_vector_type(4))) float float4v;

__device__ __forceinline__ short f2bf(float v){
  unsigned u = __float_as_uint(v);
  u += 0x7FFF + ((u >> 16) & 1);          // RNE
  return (short)(u >> 16);
}
__device__ __forceinline__ float bf2f(unsigned short u){
  return __uint_as_float(((unsigned)u) << 16);
}

// ---------- weight pack to MFMA A-frag order (bf16), 3x3 convs ----------
__global__ void k_pack(const float* __restrict__ w, unsigned short* __restrict__ o,
                       int Cin, int csz, int n){
  int idx = blockIdx.x*256 + threadIdx.x;
  if (idx >= n) return;
  int ck = idx / csz;
  int i  = idx - ck*csz;
  const float* wp = w + (size_t)ck*csz;
  int j = i & 7, lane = (i>>3)&63, mt = (i>>9)&3, p = i>>11;
  int blk = p/18, r = p - blk*18, tap = r>>1, ks = r&1;
  int co = mt*16 + (lane & 15);
  int ci = blk*64 + ks*32 + ((lane>>4)<<3) + j;
  o[idx] = (unsigned short)f2bf(wp[((size_t)co*Cin + ci)*9 + tap]);
}

// ---------- weight pack for 1x1 (Cin=64): blocks ordered ks*MT+mt ----------
__global__ void k_packpw(const float* __restrict__ w, unsigned short* __restrict__ o,
                         int Cout, int MT, int n){
  int i = blockIdx.x*256 + threadIdx.x;
  if (i >= n) return;
  int per = MT << 10;                 // 2*MT*512
  int set = i / per;
  int r = i - set*per;
  int j = r & 7, lane = (r>>3)&63, blk = r>>9;
  int ks = blk / MT, mt = blk - ks*MT;
  int co = mt*16 + (lane & 15);
  int ci = ks*32 + ((lane>>4)<<3) + j;
  float v = (co < Cout) ? w[(size_t)set*Cout*64 + co*64 + ci] : 0.f;
  o[i] = (unsigned short)f2bf(v);
}

// ---------- weight transform for fused fd1/fd2/fconv chain ----------
__global__ void k_wfdc(const float* __restrict__ fd1w, const float* __restrict__ fd2w,
                       const float* __restrict__ fcw,  const float* __restrict__ fd1g,
                       const float* __restrict__ fd2g, float* __restrict__ o){
  int i = blockIdx.x*256 + threadIdx.x;   // 2*13312
  if (i >= 26624) return;
  int br = i / 13312, r = i - br*13312;
  float v;
  if (r < 2048){
    int ci = r >> 5, j = r & 31;
    v = fd1w[br*2048 + j*64 + ci] * (fd1g[br*32 + j]*BN_SCALE);
  } else if (r < 5120){
    int rr = r - 2048; int ci = rr >> 5, j = rr & 31;
    v = fd2w[br*3072 + j*96 + ci] * (fd2g[br*32 + j]*BN_SCALE);
  } else {
    int rr = r - 5120; int ci = rr >> 6, j = rr & 63;
    v = fcw[br*8192 + j*128 + ci];
  }
  o[i] = v;
}

// ---------- fused fd1+fd2+fconv over FFT-domain pixels (f32 exact) ----------
__global__ __launch_bounds__(256) void k_fdc(
    const float* __restrict__ in, const float* __restrict__ wT,
    const float* __restrict__ bt1, const float* __restrict__ bt2,
    float* __restrict__ outp){
  __shared__ float tls[32][64];
  __shared__ float uls[32][64];
  int b = blockIdx.x, tile = blockIdx.y;
  int tid = threadIdx.x;
  int lane = tid & 63;
  int kk = __builtin_amdgcn_readfirstlane(tid >> 6);   // wave-uniform j-group
  const float* ip = in + (size_t)b*64*HWFn + tile*64 + lane;
  {
    float t[8];
    #pragma unroll
    for (int jj=0;jj<8;jj++) t[jj] = bt1[kk*8+jj];
    for (int ci=0; ci<64; ci++){
      float v = ip[(size_t)ci*HWFn];
      const float* w = wT + ci*32 + kk*8;
      #pragma unroll
      for (int jj=0;jj<8;jj++) t[jj] = fmaf(v, w[jj], t[jj]);
    }
    #pragma unroll
    for (int jj=0;jj<8;jj++){
      float a = t[jj];
      tls[kk*8+jj][lane] = (a>=0.f)? a : 0.1f*a;
    }
  }
  __syncthreads();
  {
    float u[8];
    #pragma unroll
    for (int jj=0;jj<8;jj++) u[jj] = bt2[kk*8+jj];
    for (int ci=0; ci<64; ci++){
      float v = ip[(size_t)ci*HWFn];
      const float* w = wT + 2048 + ci*32 + kk*8;
      #pragma unroll
      for (int jj=0;jj<8;jj++) u[jj] = fmaf(v, w[jj], u[jj]);
    }
    for (int ci=0; ci<32; ci++){
      float v = tls[ci][lane];
      const float* w = wT + 2048 + (64+ci)*32 + kk*8;
      #pragma unroll
      for (int jj=0;jj<8;jj++) u[jj] = fmaf(v, w[jj], u[jj]);
    }
    #pragma unroll
    for (int jj=0;jj<8;jj++){
      float a = u[jj];
      uls[kk*8+jj][lane] = (a>=0.f)? a : 0.1f*a;
    }
  }
  __syncthreads();
  float acc[16];
  #pragma unroll
  for (int jj=0;jj<16;jj++) acc[jj] = 0.f;
  for (int ci=0; ci<64; ci++){
    float v = ip[(size_t)ci*HWFn];
    const float* w = wT + 5120 + ci*64 + kk*16;
    #pragma unroll
    for (int jj=0;jj<16;jj++) acc[jj] = fmaf(v, w[jj], acc[jj]);
  }
  for (int ci=0; ci<32; ci++){
    float v = tls[ci][lane];
    const float* w = wT + 5120 + (64+ci)*64 + kk*16;
    #pragma unroll
    for (int jj=0;jj<16;jj++) acc[jj] = fmaf(v, w[jj], acc[jj]);
  }
  for (int ci=0; ci<32; ci++){
    float v = uls[ci][lane];
    const float* w = wT + 5120 + (96+ci)*64 + kk*16;
    #pragma unroll
    for (int jj=0;jj<16;jj++) acc[jj] = fmaf(v, w[jj], acc[jj]);
  }
  float* op = outp + (size_t)b*64*HWFn + tile*64 + lane;
  #pragma unroll
  for (int jj=0;jj<16;jj++)
    op[(size_t)(kk*16+jj)*HWFn] = acc[jj];
}

// ---------- MFMA 3x3 conv: Cout=64, one output row per WG ----------
constexpr int XST = 72;
__global__ __launch_bounds__(256) void k_mconv(
    const float* __restrict__ in, const float* __restrict__ in2,
    const unsigned short* __restrict__ wpk, const float* __restrict__ bias,
    const float* __restrict__ res, float* __restrict__ out,
    int nblk, int dl, int leaky){
  __shared__ short lds[3*134*XST];
  int b = blockIdx.x >> 7, y = blockIdx.x & 127;
  int tid = threadIdx.x;
  int wv = tid >> 6, lane = tid & 63;
  int nq = lane >> 4, nr = lane & 15;
  float4v acc[4][2];
  #pragma unroll
  for (int mt=0; mt<4; mt++)
    #pragma unroll
    for (int nt=0; nt<2; nt++) acc[mt][nt] = (float4v){0.f,0.f,0.f,0.f};

  for (int blk=0; blk<nblk; blk++){
    const float* src = blk ? in2 : in;
    __syncthreads();
    // interior: 4-ci groups, float4 along x, packed b64 LDS writes
    for (int e = tid; e < 3*16*32; e += 256){
      int dy = e >> 9;
      int r  = e & 511;
      int c4 = r >> 5;
      int xx = (r & 31) << 2;          // 0..124
      int yy = y + (dy-1)*dl;
      float4 v0, v1, v2, v3;
      if (yy >= 0 && yy < Hn){
        const float* sp2 = src + (((size_t)b*64 + c4*4)*Hn + yy)*Wn + xx;
        v0 = *(const float4*)(sp2);
        v1 = *(const float4*)(sp2 + HWn);
        v2 = *(const float4*)(sp2 + 2*HWn);
        v3 = *(const float4*)(sp2 + 3*HWn);
      } else {
        v0 = v1 = v2 = v3 = make_float4(0.f,0.f,0.f,0.f);
      }
      #pragma unroll
      for (int j=0; j<4; j++){
        float f0 = (&v0.x)[j], f1 = (&v1.x)[j], f2 = (&v2.x)[j], f3 = (&v3.x)[j];
        unsigned p0 = ((unsigned)(unsigned short)f2bf(f0)) | (((unsigned)(unsigned short)f2bf(f1)) << 16);
        unsigned p1 = ((unsigned)(unsigned short)f2bf(f2)) | (((unsigned)(unsigned short)f2bf(f3)) << 16);
        *(uint2*)&lds[(dy*134 + xx + 3 + j)*XST + c4*4] = make_uint2(p0, p1);
      }
    }
    for (int e = tid; e < 3*16*6; e += 256){
      int dy = e / 96; int r = e - dy*96;
      int c4 = r / 6;  int k = r - c4*6;
      int x = (k < 3) ? k : 128 + k;
      *(uint2*)&lds[(dy*134 + x)*XST + c4*4] = make_uint2(0u, 0u);
    }
    __syncthreads();
    const unsigned short* wb = wpk + (size_t)blk*36864;
    #pragma unroll 3
    for (int tap=0; tap<9; tap++){
      int dy = tap/3, dx = tap - (tap/3)*3;
      #pragma unroll
      for (int ks=0; ks<2; ks++){
        short8 a[4];
        #pragma unroll
        for (int mt=0; mt<4; mt++)
          a[mt] = *(const short8*)(wb + (((size_t)(tap*2+ks)*4+mt)<<9) + ((size_t)lane<<3));
        #pragma unroll
        for (int nt=0; nt<2; nt++){
          int x = wv*32 + nt*16 + nr + (dx-1)*dl + 3;
          short8 bf = *(const short8*)&lds[(dy*134 + x)*XST + ks*32 + nq*8];
          #pragma unroll
          for (int mt=0; mt<4; mt++)
            acc[mt][nt] = __builtin_amdgcn_mfma_f32_16x16x32_bf16(a[mt], bf, acc[mt][nt], 0, 0, 0);
        }
      }
    }
  }
  #pragma unroll
  for (int mt=0; mt<4; mt++)
  #pragma unroll
  for (int nt=0; nt<2; nt++){
    int x = wv*32 + nt*16 + nr;
    #pragma unroll
    for (int r2=0; r2<4; r2++){
      int co = mt*16 + nq*4 + r2;
      float a = acc[mt][nt][r2] + (bias ? bias[co] : 0.f);
      if (leaky) a = (a >= 0.f) ? a : 0.01f*a;
      size_t idx = (((size_t)b*64 + co)*Hn + y)*Wn + x;
      if (res) a += res[idx];
      out[idx] = a;
    }
  }
}

// ---------- fused depthwise 3x3 + pointwise 1x1 (Cin=64) via MFMA ----------
template<int MT>
__global__ __launch_bounds__(256) void k_dwpw(
    const float* __restrict__ in, const float* __restrict__ dww, const float* __restrict__ dwb,
    const unsigned short* __restrict__ pwpk, const float* __restrict__ pwb,
    float* __restrict__ out, int Cout, size_t outb, int post){
  __shared__ short tb[128*72];       // dw output [x][ci] bf16
  __shared__ float wsm[640];         // dw weights 64*9 + bias 64
  int b = blockIdx.x >> 7, y = blockIdx.x & 127;
  int tid = threadIdx.x;
  for (int i = tid; i < 640; i += 256)
    wsm[i] = (i < 576) ? dww[i] : (dwb ? dwb[i-576] : 0.f);
  __syncthreads();
  for (int e = tid; e < 2048; e += 256){
    int ci = e >> 5;
    int xx = (e & 31) << 2;            // 0..124
    const float* ip = in + ((size_t)b*64 + ci)*HWn;
    const float* wp = wsm + ci*9;
    float4 a0 = make_float4(0.f,0.f,0.f,0.f), a1 = a0, a2 = a0;
    float L0=0.f,L1=0.f,L2=0.f,R0=0.f,R1=0.f,R2=0.f;
    if (y > 0){
      const float* r = ip + (y-1)*Wn;
      a0 = *(const float4*)(r + xx);
      if (xx) L0 = r[xx-1];
      if (xx < 124) R0 = r[xx+4];
    }
    {
      const float* r = ip + y*Wn;
      a1 = *(const float4*)(r + xx);
      if (xx) L1 = r[xx-1];
      if (xx < 124) R1 = r[xx+4];
    }
    if (y < Hn-1){
      const float* r = ip + (y+1)*Wn;
      a2 = *(const float4*)(r + xx);
      if (xx) L2 = r[xx-1];
      if (xx < 124) R2 = r[xx+4];
    }
    float bb = wsm[576+ci];
    float o0=bb,o1=bb,o2=bb,o3=bb;
    float w0=wp[0],w1=wp[1],w2=wp[2];
    o0 = fmaf(w0,L0,  fmaf(w1,a0.x, fmaf(w2,a0.y, o0)));
    o1 = fmaf(w0,a0.x,fmaf(w1,a0.y, fmaf(w2,a0.z, o1)));
    o2 = fmaf(w0,a0.y,fmaf(w1,a0.z, fmaf(w2,a0.w, o2)));
    o3 = fmaf(w0,a0.z,fmaf(w1,a0.w, fmaf(w2,R0,   o3)));
    w0=wp[3];w1=wp[4];w2=wp[5];
    o0 = fmaf(w0,L1,  fmaf(w1,a1.x, fmaf(w2,a1.y, o0)));
    o1 = fmaf(w0,a1.x,fmaf(w1,a1.y, fmaf(w2,a1.z, o1)));
    o2 = fmaf(w0,a1.y,fmaf(w1,a1.z, fmaf(w2,a1.w, o2)));
    o3 = fmaf(w0,a1.z,fmaf(w1,a1.w, fmaf(w2,R1,   o3)));
    w0=wp[6];w1=wp[7];w2=wp[8];
    o0 = fmaf(w0,L2,  fmaf(w1,a2.x, fmaf(w2,a2.y, o0)));
    o1 = fmaf(w0,a2.x,fmaf(w1,a2.y, fmaf(w2,a2.z, o1)));
    o2 = fmaf(w0,a2.y,fmaf(w1,a2.z, fmaf(w2,a2.w, o2)));
    o3 = fmaf(w0,a2.z,fmaf(w1,a2.w, fmaf(w2,R2,   o3)));
    short* d = &tb[xx*72 + ci];
    d[0]   = f2bf(o0);
    d[72]  = f2bf(o1);
    d[144] = f2bf(o2);
    d[216] = f2bf(o3);
  }
  __syncthreads();
  int wv = tid>>6, lane = tid&63, nq = lane>>4, nr = lane&15;
  float4v acc[MT][2];
  #pragma unroll
  for (int mt=0; mt<MT; mt++)
    #pragma unroll
    for (int nt=0; nt<2; nt++) acc[mt][nt] = (float4v){0.f,0.f,0.f,0.f};
  #pragma unroll
  for (int ks=0; ks<2; ks++){
    short8 a[MT];
    #pragma unroll
    for (int mt=0; mt<MT; mt++)
      a[mt] = *(const short8*)(pwpk + ((ks*MT+mt)<<9) + (lane<<3));
    #pragma unroll
    for (int nt=0; nt<2; nt++){
      int x = wv*32 + nt*16 + nr;
      short8 bf = *(const short8*)&tb[x*72 + ks*32 + nq*8];
      #pragma unroll
      for (int mt=0; mt<MT; mt++)
        acc[mt][nt] = __builtin_amdgcn_mfma_f32_16x16x32_bf16(a[mt], bf, acc[mt][nt], 0, 0, 0);
    }
  }
  #pragma unroll
  for (int mt=0; mt<MT; mt++)
  #pragma unroll
  for (int nt=0; nt<2; nt++){
    int x = wv*32 + nt*16 + nr;
    #pragma unroll
    for (int r2=0; r2<4; r2++){
      int co = mt*16 + nq*4 + r2;
      if (co < Cout){
        float a = acc[mt][nt][r2] + (pwb ? pwb[co] : 0.f);
        if (post == 1) a = fminf(fmaxf(a, -1.f), 1.f);
        else if (post == 2) a = a*fminf(fmaxf(a+3.f, 0.f), 6.f)*(1.f/6.f);
        out[(size_t)b*outb + (size_t)co*HWn + y*Wn + x] = a;
      }
    }
  }
}

// ---------- fused deformable dw 3x3 + pointwise 1x1 (64 -> Cout<=16) ----------
__global__ __launch_bounds__(512) void k_defpw(
    const float* __restrict__ xg, const float* __restrict__ off, const float* __restrict__ dcnw,
    const unsigned short* __restrict__ pwpk, float* __restrict__ out,
    int Cout, size_t outb, int post){
  __shared__ unsigned short xs[5*64*130];   // [tr][ci][c] bf16 (83.2 KB)
  __shared__ short tb[128*72];
  __shared__ float wsm[576];
  int b = blockIdx.x >> 7, y = blockIdx.x & 127;
  int tid = threadIdx.x;
  int px = tid & 127, sub = tid >> 7;       // 4 threads per pixel
  for (int i = tid; i < 576; i += 512) wsm[i] = dcnw[i];
  for (int e = tid; e < 10240; e += 512){   // 5*64*32 float4 units
    int tr = e >> 11;
    int r  = e & 2047;
    int ci = r >> 5;
    int xx = (r & 31) << 2;
    int gy = min(max(y - 2 + tr, 0), Hn-1);
    float4 v = *(const float4*)&xg[(((size_t)b*64 + ci)*Hn + gy)*Wn + xx];
    unsigned short* d = &xs[(tr*64 + ci)*130 + xx];
    d[0] = (unsigned short)f2bf(v.x);
    d[1] = (unsigned short)f2bf(v.y);
    d[2] = (unsigned short)f2bf(v.z);
    d[3] = (unsigned short)f2bf(v.w);
  }
  const float* op = off + (size_t)b*18*HWn + y*Wn + px;
  int t0[9], t1[9], c0[9], c1[9];
  float w00[9], w01[9], w10[9], w11[9];
  #pragma unroll
  for (int k=0; k<9; k++){
    int ky = k/3 - 1, kx = k - (k/3)*3 - 1;
    float oy = op[(size_t)(2*k)*HWn];
    float ox = op[(size_t)(2*k+1)*HWn];
    float py = (float)(y + ky) + oy;
    float pxx = (float)(px + kx) + ox;
    float fy = floorf(py), fx = floorf(pxx);
    float wy = py - fy, wx = pxx - fx;
    int y0 = (int)fy, x0 = (int)fx;
    float vy0 = (y0 >= 0 && y0 < Hn) ? 1.f : 0.f;
    float vy1 = (y0+1 >= 0 && y0+1 < Hn) ? 1.f : 0.f;
    float vx0 = (x0 >= 0 && x0 < Wn) ? 1.f : 0.f;
    float vx1 = (x0+1 >= 0 && x0+1 < Wn) ? 1.f : 0.f;
    w00[k] = (1.f-wy)*(1.f-wx)*vy0*vx0;
    w01[k] = (1.f-wy)*wx*vy0*vx1;
    w10[k] = wy*(1.f-wx)*vy1*vx0;
    w11[k] = wy*wx*vy1*vx1;
    t0[k] = min(max(min(max(y0,   0), Hn-1) - (y-2), 0), 4);
    t1[k] = min(max(min(max(y0+1, 0), Hn-1) - (y-2), 0), 4);
    c0[k] = min(max(x0,   0), Wn-1);
    c1[k] = min(max(x0+1, 0), Wn-1);
  }
  __syncthreads();
  for (int ci = sub; ci < 64; ci += 4){
    float acc = 0.f;
    #pragma unroll
    for (int k=0; k<9; k++){
      const unsigned short* b0 = &xs[(t0[k]*64 + ci)*130];
      const unsigned short* b1 = &xs[(t1[k]*64 + ci)*130];
      float v = w00[k]*bf2f(b0[c0[k]]) + w01[k]*bf2f(b0[c1[k]])
              + w10[k]*bf2f(b1[c0[k]]) + w11[k]*bf2f(b1[c1[k]]);
      acc = fmaf(v, wsm[ci*9 + k], acc);
    }
    tb[px*72 + ci] = f2bf(acc);
  }
  __syncthreads();
  int wv = tid>>6, lane = tid&63, nq = lane>>4, nr = lane&15;
  float4v acc = (float4v){0.f,0.f,0.f,0.f};
  int x = wv*16 + nr;
  #pragma unroll
  for (int ks=0; ks<2; ks++){
    short8 a = *(const short8*)(pwpk + (ks<<9) + (lane<<3));
    short8 bf = *(const short8*)&tb[x*72 + ks*32 + nq*8];
    acc = __builtin_amdgcn_mfma_f32_16x16x32_bf16(a, bf, acc, 0, 0, 0);
  }
  #pragma unroll
  for (int r2=0; r2<4; r2++){
    int co = nq*4 + r2;
    if (co < Cout){
      float a = acc[r2];
      if (post == 2) a = a*fminf(fmaxf(a+3.f, 0.f), 6.f)*(1.f/6.f);
      out[(size_t)b*outb + (size_t)co*HWn + y*Wn + x] = a;
    }
  }
}

// ---------- depthwise 3x3, pad 1 (phase-1, 3ch) ----------
__global__ void k_dw3x3(const float* __restrict__ in, const float* __restrict__ w,
                        const float* __restrict__ bias, float* __restrict__ out, int C){
  int bc = blockIdx.x; int y = blockIdx.y; int x = threadIdx.x;
  int c = bc % C;
  const float* ip = in + (size_t)bc*HWn;
  const float* wp = w + c*9;
  float acc = bias ? bias[c] : 0.f;
  #pragma unroll
  for (int ky=0; ky<3; ky++){
    int yy = y + ky - 1; if (yy < 0 || yy >= Hn) continue;
    #pragma unroll
    for (int kx=0; kx<3; kx++){
      int xx = x + kx - 1; if (xx < 0 || xx >= Wn) continue;
      acc = fmaf(ip[yy*Wn+xx], wp[ky*3+kx], acc);
    }
  }
  out[(size_t)bc*HWn + y*Wn + x] = acc;
}

// ---------- pointwise 1x1, register-tiled (phase-1 only) ----------
template<int CT>
__global__ void k_pwt(const float* __restrict__ in, const float* __restrict__ wg,
                      const float* __restrict__ bias, const float* __restrict__ bng,
                      const float* __restrict__ bnb, float* __restrict__ out,
                      int Cin, int Cout, int npix, int inb, int outb, int post, float slope){
  extern __shared__ float wsm[];
  int nt = (Cout + CT - 1)/CT;
  int b = blockIdx.x / nt, t = blockIdx.x - b*nt;
  int co0 = t*CT;
  for (int i = threadIdx.x; i < CT*Cin; i += 256){
    int co = i / Cin;
    wsm[i] = (co0 + co < Cout) ? wg[(size_t)(co0+co)*Cin + (i - co*Cin)] : 0.f;
  }
  __syncthreads();
  int p = blockIdx.y*256 + threadIdx.x;
  if (p >= npix) return;
  const float* ip = in + (size_t)b*inb + p;
  float acc[CT];
  #pragma unroll
  for (int j=0; j<CT; j++) acc[j] = 0.f;
  for (int ci=0; ci<Cin; ci++){
    float v = ip[(size_t)ci*npix];
    #pragma unroll
    for (int j=0; j<CT; j++) acc[j] = fmaf(v, wsm[j*Cin+ci], acc[j]);
  }
  #pragma unroll
  for (int j=0; j<CT; j++){
    int co = co0 + j;
    if (co < Cout){
      float a = acc[j] + (bias ? bias[co] : 0.f);
      if (bng) a = a*(bng[co]*BN_SCALE) + bnb[co];
      if (post == 1) a = fminf(fmaxf(a, -1.f), 1.f);
      else if (post == 2) a = a*fminf(fmaxf(a+3.f, 0.f), 6.f)*(1.f/6.f);
      else if (post == 3) a = (a >= 0.f) ? a : a*slope;
      out[(size_t)b*outb + (size_t)co*npix + p] = a;
    }
  }
}

// ---------- deformable depthwise 3x3 (phase-1, 3ch) ----------
__global__ void k_deform(const float* __restrict__ x, const float* __restrict__ off,
                         const float* __restrict__ w, float* __restrict__ out, int C){
  int bc = blockIdx.x; int b = bc / C; int c = bc - b*C;
  int y = blockIdx.y; int x0 = threadIdx.x;
  const float* xp = x + (size_t)bc*HWn;
  const float* op = off + (size_t)b*18*HWn + y*Wn + x0;
  const float* wp = w + c*9;
  float acc = 0.f;
  #pragma unroll
  for (int k=0; k<9; k++){
    int ky = k/3 - 1, kx = k - (k/3)*3 - 1;
    float oy = op[(size_t)(2*k)*HWn];
    float ox = op[(size_t)(2*k+1)*HWn];
    float py = (float)y + (float)ky + oy;
    float px = (float)x0 + (float)kx + ox;
    float fy = floorf(py), fx = floorf(px);
    float wy = py - fy, wx = px - fx;
    int y0 = (int)fy, xx0 = (int)fx;
    float val = 0.f;
    #pragma unroll
    for (int dy=0; dy<2; dy++){
      int iy = y0 + dy; if (iy < 0 || iy >= Hn) continue;
      float wyv = dy ? wy : (1.f - wy);
      #pragma unroll
      for (int dx=0; dx<2; dx++){
        int ix = xx0 + dx; if (ix < 0 || ix >= Wn) continue;
        float wxv = dx ? wx : (1.f - wx);
        val = fmaf(xp[iy*Wn+ix], wyv*wxv, val);
      }
    }
    acc = fmaf(val, wp[k], acc);
  }
  out[(size_t)bc*HWn + y*Wn + x0] = acc;
}

// ---------- small direct conv (final 6->3) ----------
__global__ void k_conv3x3s(const float* __restrict__ in, const float* __restrict__ wgt,
                           const float* __restrict__ bias, const float* __restrict__ res,
                           float* __restrict__ out, int Cin, int Cout){
  int g = blockIdx.x;
  int b = g / Cout; int o0 = g - b*Cout;
  int y = blockIdx.y, x = threadIdx.x;
  float acc = bias ? bias[o0] : 0.f;
  for (int ci=0; ci<Cin; ci++){
    const float* iip = in + ((size_t)b*Cin + ci)*HWn;
    const float* wp = wgt + ((size_t)o0*Cin + ci)*9;
    #pragma unroll
    for (int ky=0; ky<3; ky++){
      int yy = y + ky - 1; if (yy < 0 || yy >= Hn) continue;
      #pragma unroll
      for (int kx=0; kx<3; kx++){
        int xx = x + kx - 1; if (xx < 0 || xx >= Wn) continue;
        acc = fmaf(iip[yy*Wn+xx], wp[ky*3+kx], acc);
      }
    }
  }
  size_t idx = ((size_t)b*Cout + o0)*HWn + y*Wn + x;
  if (res) acc += res[idx];
  out[idx] = acc;
}

// ---------- fused cross-attention: one WG per (b,h), 512 threads ----------
__global__ __launch_bounds__(512) void k_attn(
    const float* __restrict__ q, const float* __restrict__ k,
    const float* __restrict__ v, float* __restrict__ o){
  __shared__ float qs[64][129];
  __shared__ float ks[64][129];
  __shared__ float vs[64][129];
  __shared__ float ps[64][66];
  int bh = blockIdx.x; int b = bh >> 7, h = bh & 127;
  size_t base = ((size_t)b*64*128 + h)*128;
  int tid = threadIdx.x;
  for (int e = tid; e < 8192; e += 512){
    int c = e >> 7, w = e & 127;
    size_t g = base + (size_t)c*HWn + w;
    qs[c][w] = q[g]; ks[c][w] = k[g]; vs[c][w] = v[g];
  }
  __syncthreads();
  {
    int c0 = (tid >> 4) << 1, d0 = (tid & 15) << 2;   // 2x4 score tile
    float acc[2][4];
    #pragma unroll
    for (int a=0; a<2; a++)
      #pragma unroll
      for (int bb=0; bb<4; bb++) acc[a][bb] = 0.f;
    for (int i=0; i<128; i++){
      float qv[2], kv[4];
      #pragma unroll
      for (int a=0; a<2; a++) qv[a] = qs[c0+a][i];
      #pragma unroll
      for (int bb=0; bb<4; bb++) kv[bb] = ks[d0+bb][i];
      #pragma unroll
      for (int a=0; a<2; a++)
        #pragma unroll
        for (int bb=0; bb<4; bb++) acc[a][bb] = fmaf(qv[a], kv[bb], acc[a][bb]);
    }
    #pragma unroll
    for (int a=0; a<2; a++)
      #pragma unroll
      for (int bb=0; bb<4; bb++)
        ps[c0+a][d0+bb] = acc[a][bb] * 0.35355339059327373f;
  }
  __syncthreads();
  {
    int wv = tid >> 6, lane = tid & 63;               // 8 waves x 8 rows
    for (int it=0; it<8; it++){
      int row = wv*8 + it;
      float vv = ps[row][lane];
      float m = vv;
      #pragma unroll
      for (int off=32; off; off>>=1) m = fmaxf(m, __shfl_xor(m, off));
      float e = expf(vv - m);
      float s = e;
      #pragma unroll
      for (int off=32; off; off>>=1) s += __shfl_xor(s, off);
      ps[row][lane] = e / s;
    }
  }
  __syncthreads();
  {
    int c0 = (tid >> 4) << 1, w0 = (tid & 15) << 3;   // 2x8 output tile
    float acc[2][8];
    #pragma unroll
    for (int a=0; a<2; a++)
      #pragma unroll
      for (int j=0; j<8; j++) acc[a][j] = 0.f;
    for (int d=0; d<64; d++){
      float pv[2], vv[8];
      #pragma unroll
      for (int a=0; a<2; a++) pv[a] = ps[c0+a][d];
      #pragma unroll
      for (int j=0; j<8; j++) vv[j] = vs[d][w0+j];
      #pragma unroll
      for (int a=0; a<2; a++)
        #pragma unroll
        for (int j=0; j<8; j++) acc[a][j] = fmaf(pv[a], vv[j], acc[a][j]);
    }
    #pragma unroll
    for (int a=0; a<2; a++)
      #pragma unroll
      for (int j=0; j<8; j++)
        o[base + (size_t)(c0+a)*HWn + w0 + j] = acc[a][j];
  }
}

// ============ wave-level 128-pt FFT (no barriers, register-resident) ============
__device__ __forceinline__ float2 cmul(float2 a, float2 b){
  return make_float2(a.x*b.x - a.y*b.y, a.x*b.y + a.y*b.x);
}

// two interleaved 128-pt FFTs: (z[0],z[1]) and (z[2],z[3]) — 4 chains in flight
__device__ __forceinline__ void wfft4(float2* z, const float2* twl, int l){
  #pragma unroll
  for (int q=0; q<2; q++){
    float dx = z[2*q].x - z[2*q+1].x, dy = z[2*q].y - z[2*q+1].y;
    z[2*q].x += z[2*q+1].x; z[2*q].y += z[2*q+1].y;
    z[2*q+1] = cmul(make_float2(dx, dy), twl[6]);
  }
  #pragma unroll
  for (int s = 5; s >= 0; --s){
    int h = 1 << s;
    bool up = (l & h) != 0;
    float2 w = twl[s];
    #pragma unroll
    for (int q=0; q<4; q++){
      float ox = __shfl_xor(z[q].x, h), oy = __shfl_xor(z[q].y, h);
      float sx = up ? ox - z[q].x : z[q].x + ox;
      float sy = up ? oy - z[q].y : z[q].y + oy;
      float2 t = cmul(make_float2(sx, sy), w);
      z[q].x = up ? t.x : sx;  z[q].y = up ? t.y : sy;
    }
  }
}

__device__ __forceinline__ void wreorder(float2 z0, float2 z1, float2& n0, float2& n1, int l){
  int a = (int)(__brev((unsigned)(l >> 1)) >> 26);
  float p0x = __shfl(z0.x, a),   p0y = __shfl(z0.y, a);
  float p1x = __shfl(z1.x, a),   p1y = __shfl(z1.y, a);
  float q0x = __shfl(z0.x, a+1), q0y = __shfl(z0.y, a+1);
  float q1x = __shfl(z1.x, a+1), q1y = __shfl(z1.y, a+1);
  bool odd = (l & 1) != 0;
  n0 = odd ? make_float2(p1x, p1y) : make_float2(p0x, p0y);
  n1 = odd ? make_float2(q1x, q1y) : make_float2(q0x, q0y);
}

// ---------- fused rfft2 + mag/pha: 512 threads (8 waves) for TLP ----------
__global__ __launch_bounds__(512) void k_fft2(
    const float* __restrict__ x, float* __restrict__ mag, float* __restrict__ pha){
  __shared__ float spr[8320];
  __shared__ float spi[8320];
  int img = blockIdx.x;
  int tid = threadIdx.x;
  int wv = tid >> 6, l = tid & 63;
  float2 twl[7];
  #pragma unroll
  for (int s = 0; s < 7; ++s){
    int jh = (l & ((1 << s) - 1)) << (6 - s);
    float sv, cv; sincosf(-TWOPI * (float)jh * (1.f/128.f), &sv, &cv);
    twl[s] = make_float2(cv, sv);
  }
  const float* xp = x + (size_t)img*HWn;
  for (int f = wv; f < 32; f += 8){
    int fB = f + 32;
    float2 z[4];
    {
      const float* a0 = xp + (2*f)*Wn;  const float* a1 = a0 + Wn;
      const float* b0 = xp + (2*fB)*Wn; const float* b1 = b0 + Wn;
      z[0] = make_float2(a0[l],      a1[l]);
      z[1] = make_float2(a0[64 + l], a1[64 + l]);
      z[2] = make_float2(b0[l],      b1[l]);
      z[3] = make_float2(b0[64 + l], b1[64 + l]);
    }
    wfft4(z, twl, l);
    #pragma unroll
    for (int q=0; q<2; q++){
      int ff = q ? fB : f;
      float2 n0, n1; wreorder(z[2*q], z[2*q+1], n0, n1, l);
      float zhx = __shfl(n1.x, (64 - l) & 63);
      float zhy = __shfl(n1.y, (64 - l) & 63);
      float2 Zn = (l == 0) ? n0 : make_float2(zhx, zhy);
      int iA = (2*ff)*65 + l, iB = (2*ff+1)*65 + l;
      spr[iA] = 0.5f*(n0.x + Zn.x);  spi[iA] = 0.5f*(n0.y - Zn.y);
      spr[iB] = 0.5f*(n0.y + Zn.y);  spi[iB] = 0.5f*(Zn.x - n0.x);
      if (l == 0){
        spr[(2*ff)*65 + 64]   = n1.x;  spi[(2*ff)*65 + 64]   = 0.f;
        spr[(2*ff+1)*65 + 64] = n1.y;  spi[(2*ff+1)*65 + 64] = 0.f;
      }
    }
  }
  __syncthreads();
  for (int c = wv; c < 33; c += 8){
    int cB = c + 33;
    bool h2 = cB < 65;
    int cB_s = h2 ? cB : c;
    float2 z[4];
    z[0] = make_float2(spr[l*65 + c],        spi[l*65 + c]);
    z[1] = make_float2(spr[(64 + l)*65 + c], spi[(64 + l)*65 + c]);
    z[2] = make_float2(spr[l*65 + cB_s],        spi[l*65 + cB_s]);
    z[3] = make_float2(spr[(64 + l)*65 + cB_s], spi[(64 + l)*65 + cB_s]);
    wfft4(z, twl, l);
    {
      float2 n0, n1; wreorder(z[0], z[1], n0, n1, l);
      spr[l*65 + c]        = sqrtf(n0.x*n0.x + n0.y*n0.y);
      spi[l*65 + c]        = atan2f(n0.y, n0.x);
      spr[(64 + l)*65 + c] = sqrtf(n1.x*n1.x + n1.y*n1.y);
      spi[(64 + l)*65 + c] = atan2f(n1.y, n1.x);
    }
    if (h2){
      float2 n0, n1; wreorder(z[2], z[3], n0, n1, l);
      spr[l*65 + cB]        = sqrtf(n0.x*n0.x + n0.y*n0.y);
      spi[l*65 + cB]        = atan2f(n0.y, n0.x);
      spr[(64 + l)*65 + cB] = sqrtf(n1.x*n1.x + n1.y*n1.y);
      spi[(64 + l)*65 + cB] = atan2f(n1.y, n1.x);
    }
  }
  __syncthreads();
  float* mp = mag + (size_t)img*HWFn;
  float* pp = pha + (size_t)img*HWFn;
  for (int i = tid; i < 8320; i += 512){
    mp[i] = spr[i]; pp[i] = spi[i];
  }
}

// ---------- fused irfft2 + residual add: 512 threads ----------
__global__ __launch_bounds__(512) void k_ifft2(
    const float* __restrict__ mo, const float* __restrict__ po,
    const float* __restrict__ hsrc, float* __restrict__ outp){
  __shared__ float spr[8320];
  __shared__ float spi[8320];
  int img = blockIdx.x;
  int tid = threadIdx.x;
  int wv = tid >> 6, l = tid & 63;
  float2 twl[7];
  #pragma unroll
  for (int s = 0; s < 7; ++s){
    int jh = (l & ((1 << s) - 1)) << (6 - s);
    float sv, cv; sincosf(TWOPI * (float)jh * (1.f/128.f), &sv, &cv);
    twl[s] = make_float2(cv, sv);
  }
  const float* mp = mo + (size_t)img*HWFn;
  const float* pp = po + (size_t)img*HWFn;
  for (int i = tid; i < 8320; i += 512){
    float m = mp[i], p = pp[i];
    float sv, cv; sincosf(p, &sv, &cv);
    spr[i] = m*cv; spi[i] = m*sv;
  }
  __syncthreads();
  for (int c = wv; c < 33; c += 8){
    int cB = c + 33;
    bool h2 = cB < 65;
    int cB_s = h2 ? cB : c;
    float2 z[4];
    z[0] = make_float2(spr[l*65 + c],        spi[l*65 + c]);
    z[1] = make_float2(spr[(64 + l)*65 + c], spi[(64 + l)*65 + c]);
    z[2] = make_float2(spr[l*65 + cB_s],        spi[l*65 + cB_s]);
    z[3] = make_float2(spr[(64 + l)*65 + cB_s], spi[(64 + l)*65 + cB_s]);
    wfft4(z, twl, l);
    {
      float2 n0, n1; wreorder(z[0], z[1], n0, n1, l);
      spr[l*65 + c] = n0.x;        spi[l*65 + c] = n0.y;
      spr[(64 + l)*65 + c] = n1.x; spi[(64 + l)*65 + c] = n1.y;
    }
    if (h2){
      float2 n0, n1; wreorder(z[2], z[3], n0, n1, l);
      spr[l*65 + cB] = n0.x;        spi[l*65 + cB] = n0.y;
      spr[(64 + l)*65 + cB] = n1.x; spi[(64 + l)*65 + cB] = n1.y;
    }
  }
  __syncthreads();
  const float scl = 1.f/16384.f;
  for (int f = wv; f < 32; f += 8){
    int fB = f + 32;
    float2 z[4];
    #pragma unroll
    for (int q=0; q<2; q++){
      int ff = q ? fB : f;
      int iA = (2*ff)*65 + l, iB = (2*ff+1)*65 + l;
      float2 A  = make_float2(spr[iA], spi[iA]);
      float2 Bv = make_float2(spr[iB], spi[iB]);
      if (l == 0){ A.y = 0.f; Bv.y = 0.f; }
      z[2*q] = make_float2(A.x - Bv.y, A.y + Bv.x);
      int lm = 64 - l;
      float2 Am = make_float2(spr[(2*ff)*65 + lm],   spi[(2*ff)*65 + lm]);
      float2 Bm = make_float2(spr[(2*ff+1)*65 + lm], spi[(2*ff+1)*65 + lm]);
      z[2*q+1] = (l == 0) ? make_float2(Am.x, Bm.x)
                          : make_float2(Am.x + Bm.y, Bm.x - Am.y);
    }
    wfft4(z, twl, l);
    #pragma unroll
    for (int q=0; q<2; q++){
      int ff = q ? fB : f;
      float2 n0, n1; wreorder(z[2*q], z[2*q+1], n0, n1, l);
      size_t g0 = (size_t)img*HWn + (size_t)(2*ff)*Wn + l;
      size_t g1 = g0 + Wn;
      outp[g0]      = n0.x*scl + hsrc[g0];
      outp[g0 + 64] = n1.x*scl + hsrc[g0 + 64];
      outp[g1]      = n0.y*scl + hsrc[g1];
      outp[g1 + 64] = n1.y*scl + hsrc[g1 + 64];
    }
  }
}

} // namespace

extern "C" void kernel_launch(void* const* d_in, const int* in_sizes, int n_in,
                              void* d_out, int out_size, void* d_ws, size_t ws_size,
                              hipStream_t stream){
  const float *xf   =(const float*)d_in[0],  *chodw=(const float*)d_in[1],
              *chopw=(const float*)d_in[2],  *chdcn=(const float*)d_in[3],
              *chpw =(const float*)d_in[4],  *ctodw=(const float*)d_in[5],
              *ctopw=(const float*)d_in[6],  *ctdcn=(const float*)d_in[7],
              *ctpw =(const float*)d_in[8],  *dbw  =(const float*)d_in[9],
              *dbb  =(const float*)d_in[10], *cadw =(const float*)d_in[11],
              *cadb =(const float*)d_in[12], *capw =(const float*)d_in[13],
              *capb =(const float*)d_in[14], *hhw  =(const float*)d_in[15],
              *hhb  =(const float*)d_in[16], *fd1w =(const float*)d_in[17],
              *fd2w =(const float*)d_in[18], *fd1g =(const float*)d_in[19],
              *fd1bt=(const float*)d_in[20], *fd2g =(const float*)d_in[21],
              *fd2bt=(const float*)d_in[22], *fcw  =(const float*)d_in[23],
              *cw   =(const float*)d_in[24], *cb   =(const float*)d_in[25];

  constexpr size_t M = 1048576;            // one batch x 64ch x HW (floats)
  float* ws = (float*)d_ws;
  float* h     = ws;                       // 12*M
  float* fftHL = ws + 12*M;                // 4*M
  float* cat6  = ws + 16*M;                // 1,179,648
  unsigned short* wpkDB = (unsigned short*)(cat6 + 1179648);
  unsigned short* wpkHH = wpkDB + 552960;
  float* wfdc = (float*)(wpkHH + 73728);   // 26624 floats (2 branches x 13312)
  float* P = cat6 + 1179648 + 313344 + 26624;   // pool

  const int NB = (ws_size >= 266018816ull) ? 4 : (ws_size >= 173850624ull) ? 2 : 1;
  const size_t S = (size_t)NB*M;
  float* kb  = P;        float* vb  = P + S;   float* qb  = P + 2*S;
  float* qsl = P + 3*S;  // packed pw weights live here (written after phase 2)
  float* aA  = P + 4*S;  float* aB  = P + 5*S;
  float* aC  = P + 6*S;  float* hh1 = P + 7*S; float* sA  = P + 8*S;
  float* sB  = P + 9*S;  float* dbuf= P + 10*S;
  float* X   = P + 11*S;
  unsigned short* pwpkCA = (unsigned short*)qsl;      // 6*4096
  unsigned short* pwpkTO = pwpkCA + 24576;            // 2048
  unsigned short* pwpkTP = pwpkTO + 2048;             // 1024
  // phase-1 aliases
  float* dwb3 = P; float* offb12 = P + 589824; float* yb3 = P + 4128768;

  float* out = (float*)d_out;
  float* out0 = out;
  float* out1 = out + 589824;
  float* out2 = out + 589824 + 6389760;

  auto PW = [&](const float* in, const float* wg, const float* bi, const float* g, const float* bt,
                float* o, int B, int Ci, int Co, int npix, int inb, int outb, int post, float slope){
    int py = (npix + 255)/256;
    if (Co > 32){
      k_pwt<32><<<dim3(B*2, py), 256, 32*Ci*4, stream>>>(in, wg, bi, g, bt, o, Ci, Co, npix, inb, outb, post, slope);
    } else if (Co > 18){
      k_pwt<32><<<dim3(B, py), 256, 32*Ci*4, stream>>>(in, wg, bi, g, bt, o, Ci, Co, npix, inb, outb, post, slope);
    } else if (Co > 3){
      k_pwt<18><<<dim3(B, py), 256, 18*Ci*4, stream>>>(in, wg, bi, g, bt, o, Ci, Co, npix, inb, outb, post, slope);
    } else {
      k_pwt<3><<<dim3(B, py), 256, 3*Ci*4, stream>>>(in, wg, bi, g, bt, o, Ci, Co, npix, inb, outb, post, slope);
    }
  };
  auto MCONV = [&](const float* in, const float* in2, const unsigned short* wp, const float* bi,
                   const float* res, float* o, int B, int nblk, int dl, int lk){
    k_mconv<<<B*128, 256, 0, stream>>>(in, in2, wp, bi, res, o, nblk, dl, lk);
  };
  auto DILm = [&](const float* in, int set, const float* bset, int B){
    const unsigned short* w5 = wpkDB + (size_t)set*5*36864;
    MCONV(in, nullptr, w5,          bset,      nullptr, sA,   B, 1, 1, 1);
    MCONV(sA, nullptr, w5+36864,    bset+64,   nullptr, sB,   B, 1, 2, 1);
    MCONV(sB, nullptr, w5+2*36864,  bset+128,  nullptr, sA,   B, 1, 3, 1);
    MCONV(sA, nullptr, w5+3*36864,  bset+192,  nullptr, sB,   B, 1, 2, 1);
    MCONV(sB, nullptr, w5+4*36864,  bset+256,  in,      dbuf, B, 1, 1, 0);
  };
  auto DCONVm = [&](const float* in, int idx, float* o, int B){
    k_dwpw<4><<<B*128, 256, 0, stream>>>(in, cadw + idx*576, cadb + idx*64,
        pwpkCA + (size_t)idx*4096, capb + idx*64, o, 64, (size_t)64*HWn, 0);
  };
  auto ATTNm = [&](const float* qsrc, int qidx, float* o, int B){
    DCONVm(qsrc, qidx, qb, B);
    k_attn<<<B*128, 512, 0, stream>>>(qb, kb, vb, o);
  };
  auto PEMBEDm = [&](const float* in, float* outSlice, int B){
    k_dwpw<2><<<B*128, 256, 0, stream>>>(in, ctodw, nullptr, pwpkTO, nullptr,
        X, 18, (size_t)18*HWn, 1);
    k_defpw<<<B*128, 512, 0, stream>>>(in, X, ctdcn, pwpkTP, outSlice, 3, (size_t)6*HWn, 2);
  };

  // ===== Pack 3x3 conv weights + fdc weight transform =====
  k_pack<<<(552960 + 255)/256, 256, 0, stream>>>(dbw, wpkDB, 64, 36864, 552960);
  k_pack<<<288, 256, 0, stream>>>(hhw, wpkHH, 128, 73728, 73728);
  k_wfdc<<<104, 256, 0, stream>>>(fd1w, fd2w, fcw, fd1g, fd2g, wfdc);

  // ===== Phase 1: patch_embed(ch) -> h (3-channel, unfused path) =====
  k_dw3x3<<<dim3(36, Hn), 128, 0, stream>>>(xf, chodw, nullptr, dwb3, 3);
  PW(dwb3, chopw, nullptr, nullptr, nullptr, offb12, 12, 3, 18, HWn, 3*HWn, 18*HWn, 1, 0.f);
  k_deform<<<dim3(36, Hn), 128, 0, stream>>>(xf, offb12, chdcn, yb3, 3);
  PW(yb3, chpw, nullptr, nullptr, nullptr, h, 12, 3, 64, HWn, 3*HWn, 64*HWn, 2, 0.f);

  // ===== Phase 2: fft_block (wave-register 2-D FFT + fused branch chain) =====
  if (NB == 4){
    float* mB = P;                 // [12][64][8320]
    float* pB = P + 6389760;
    k_fft2<<<768, 512, 0, stream>>>(h, mB, pB);
    k_fdc<<<dim3(12, 130), 256, 0, stream>>>(mB, wfdc,         fd1bt,      fd2bt,      out1);
    k_fdc<<<dim3(12, 130), 256, 0, stream>>>(pB, wfdc + 13312, fd1bt + 32, fd2bt + 32, out2);
    k_ifft2<<<256, 512, 0, stream>>>(out1, out2, h, fftHL);
  } else {
    // 3 chunks of 4 batches (works for NB=1 and NB=2; pool >= 4.26M floats)
    float* mB = P;                 // [4][64][8320]
    float* pB = P + 2129920;
    for (int c=0; c<3; c++){
      const float* hsrc = h + (size_t)c*4*M;
      float* o1 = out1 + (size_t)c*2129920;
      float* o2 = out2 + (size_t)c*2129920;
      k_fft2<<<256, 512, 0, stream>>>(hsrc, mB, pB);
      k_fdc<<<dim3(4, 130), 256, 0, stream>>>(mB, wfdc,         fd1bt,      fd2bt,      o1);
      k_fdc<<<dim3(4, 130), 256, 0, stream>>>(pB, wfdc + 13312, fd1bt + 32, fd2bt + 32, o2);
      if (c == 0)
        k_ifft2<<<256, 512, 0, stream>>>(out1, out2, h, fftHL);
    }
  }

  // ===== Pack 1x1 pw weights (into pool slot; free after phase 2) =====
  k_packpw<<<96, 256, 0, stream>>>(capw,  pwpkCA, 64, 4, 24576);
  k_packpw<<<8,  256, 0, stream>>>(ctopw, pwpkTO, 18, 2, 2048);
  k_packpw<<<4,  256, 0, stream>>>(ctpw,  pwpkTP, 3,  1, 1024);

  // ===== Phases 3-5 in groups of NB batches =====
  for (int g0=0; g0<4; g0+=NB){
    const float* hHL = h + (size_t)g0*M;
    const float* hLH = h + (size_t)(4+g0)*M;
    const float* hHH = h + (size_t)(8+g0)*M;
    const float* fHL = fftHL + (size_t)g0*M;
    DCONVm(hHH, 1, kb, NB);
    DCONVm(hHH, 2, vb, NB);
    ATTNm(hLH, 0, aA, NB);                       // x_HH_LH (== f_HH_LH)
    DCONVm(hHH, 4, kb, NB);
    DCONVm(hHH, 5, vb, NB);
    ATTNm(hHL, 3, aB, NB);                       // x_HH_HL
    ATTNm(fHL, 3, aC, NB);                       // f_HH_HL
    // x_HH2 path
    MCONV(aA, aB, wpkHH, hhb, nullptr, hh1, NB, 2, 1, 0);
    DILm(hh1, 2, dbb + 2*320, NB);
    PEMBEDm(dbuf, cat6 + (size_t)((8+g0)*6)*HWn, NB);
    // f_HH2 path
    MCONV(aA, aC, wpkHH, hhb, nullptr, hh1, NB, 2, 1, 0);
    DILm(hh1, 2, dbb + 2*320, NB);
    PEMBEDm(dbuf, cat6 + (size_t)((8+g0)*6+3)*HWn, NB);
    // x_HL2 / x_LH2
    DILm(hHL, 1, dbb + 320, NB);
    PEMBEDm(dbuf, cat6 + (size_t)(g0*6)*HWn, NB);
    DILm(hLH, 0, dbb, NB);
    PEMBEDm(dbuf, cat6 + (size_t)((4+g0)*6)*HWn, NB);
    // fft_HL / fft_LH passthroughs
    PEMBEDm(fHL, cat6 + (size_t)(g0*6+3)*HWn, NB);
    PEMBEDm(hLH, cat6 + (size_t)((4+g0)*6+3)*HWn, NB);
  }

  // ===== Final conv + residual -> out0 =====
  k_conv3x3s<<<dim3(36, Hn), 128, 0, stream>>>(cat6, cw, cb, xf, out0, 6, 3);
}

// Round 12
// 1513.829 us; speedup vs baseline: 1.1062x; 1.0887x over previous
//
#include <hip/hip_runtime.h>

namespace {

constexpr int Hn = 128, Wn = 128, HWn = 16384, HWFn = 8320;
constexpr float TWOPI = 6.2831853071795864769f;
constexpr float BN_SCALE = 0.99999500003749968f;   // 1/sqrt(1+1e-5)

typedef __attribute__((ext_vector_type(8))) short short8;
typedef __attribute__((ext_vector_type(4))) float float4v;

__device__ __forceinline__ short f2bf(float v){
  unsigned u = __float_as_uint(v);
  u += 0x7FFF + ((u >> 16) & 1);          // RNE
  return (short)(u >> 16);
}
__device__ __forceinline__ float bf2f(unsigned short u){
  return __uint_as_float(((unsigned)u) << 16);
}

// ---------- weight pack to MFMA A-frag order (bf16), 3x3 convs ----------
__global__ void k_pack(const float* __restrict__ w, unsigned short* __restrict__ o,
                       int Cin, int csz, int n){
  int idx = blockIdx.x*256 + threadIdx.x;
  if (idx >= n) return;
  int ck = idx / csz;
  int i  = idx - ck*csz;
  const float* wp = w + (size_t)ck*csz;
  int j = i & 7, lane = (i>>3)&63, mt = (i>>9)&3, p = i>>11;
  int blk = p/18, r = p - blk*18, tap = r>>1, ks = r&1;
  int co = mt*16 + (lane & 15);
  int ci = blk*64 + ks*32 + ((lane>>4)<<3) + j;
  o[idx] = (unsigned short)f2bf(wp[((size_t)co*Cin + ci)*9 + tap]);
}

// ---------- weight pack for 1x1 (Cin=64): blocks ordered ks*MT+mt ----------
__global__ void k_packpw(const float* __restrict__ w, unsigned short* __restrict__ o,
                         int Cout, int MT, int n){
  int i = blockIdx.x*256 + threadIdx.x;
  if (i >= n) return;
  int per = MT << 10;                 // 2*MT*512
  int set = i / per;
  int r = i - set*per;
  int j = r & 7, lane = (r>>3)&63, blk = r>>9;
  int ks = blk / MT, mt = blk - ks*MT;
  int co = mt*16 + (lane & 15);
  int ci = ks*32 + ((lane>>4)<<3) + j;
  float v = (co < Cout) ? w[(size_t)set*Cout*64 + co*64 + ci] : 0.f;
  o[i] = (unsigned short)f2bf(v);
}

// ---------- weight transform for fused fd1/fd2/fconv chain ----------
__global__ void k_wfdc(const float* __restrict__ fd1w, const float* __restrict__ fd2w,
                       const float* __restrict__ fcw,  const float* __restrict__ fd1g,
                       const float* __restrict__ fd2g, float* __restrict__ o){
  int i = blockIdx.x*256 + threadIdx.x;   // 2*13312
  if (i >= 26624) return;
  int br = i / 13312, r = i - br*13312;
  float v;
  if (r < 2048){
    int ci = r >> 5, j = r & 31;
    v = fd1w[br*2048 + j*64 + ci] * (fd1g[br*32 + j]*BN_SCALE);
  } else if (r < 5120){
    int rr = r - 2048; int ci = rr >> 5, j = rr & 31;
    v = fd2w[br*3072 + j*96 + ci] * (fd2g[br*32 + j]*BN_SCALE);
  } else {
    int rr = r - 5120; int ci = rr >> 6, j = rr & 63;
    v = fcw[br*8192 + j*128 + ci];
  }
  o[i] = v;
}

// ---------- fused fd1+fd2+fconv over FFT-domain pixels (f32 exact) ----------
__global__ __launch_bounds__(256) void k_fdc(
    const float* __restrict__ in, const float* __restrict__ wT,
    const float* __restrict__ bt1, const float* __restrict__ bt2,
    float* __restrict__ outp){
  __shared__ float tls[32][64];
  __shared__ float uls[32][64];
  int b = blockIdx.x, tile = blockIdx.y;
  int tid = threadIdx.x;
  int lane = tid & 63;
  int kk = __builtin_amdgcn_readfirstlane(tid >> 6);   // wave-uniform j-group
  const float* ip = in + (size_t)b*64*HWFn + tile*64 + lane;
  {
    float t[8];
    #pragma unroll
    for (int jj=0;jj<8;jj++) t[jj] = bt1[kk*8+jj];
    for (int ci=0; ci<64; ci++){
      float v = ip[(size_t)ci*HWFn];
      const float* w = wT + ci*32 + kk*8;
      #pragma unroll
      for (int jj=0;jj<8;jj++) t[jj] = fmaf(v, w[jj], t[jj]);
    }
    #pragma unroll
    for (int jj=0;jj<8;jj++){
      float a = t[jj];
      tls[kk*8+jj][lane] = (a>=0.f)? a : 0.1f*a;
    }
  }
  __syncthreads();
  {
    float u[8];
    #pragma unroll
    for (int jj=0;jj<8;jj++) u[jj] = bt2[kk*8+jj];
    for (int ci=0; ci<64; ci++){
      float v = ip[(size_t)ci*HWFn];
      const float* w = wT + 2048 + ci*32 + kk*8;
      #pragma unroll
      for (int jj=0;jj<8;jj++) u[jj] = fmaf(v, w[jj], u[jj]);
    }
    for (int ci=0; ci<32; ci++){
      float v = tls[ci][lane];
      const float* w = wT + 2048 + (64+ci)*32 + kk*8;
      #pragma unroll
      for (int jj=0;jj<8;jj++) u[jj] = fmaf(v, w[jj], u[jj]);
    }
    #pragma unroll
    for (int jj=0;jj<8;jj++){
      float a = u[jj];
      uls[kk*8+jj][lane] = (a>=0.f)? a : 0.1f*a;
    }
  }
  __syncthreads();
  float acc[16];
  #pragma unroll
  for (int jj=0;jj<16;jj++) acc[jj] = 0.f;
  for (int ci=0; ci<64; ci++){
    float v = ip[(size_t)ci*HWFn];
    const float* w = wT + 5120 + ci*64 + kk*16;
    #pragma unroll
    for (int jj=0;jj<16;jj++) acc[jj] = fmaf(v, w[jj], acc[jj]);
  }
  for (int ci=0; ci<32; ci++){
    float v = tls[ci][lane];
    const float* w = wT + 5120 + (64+ci)*64 + kk*16;
    #pragma unroll
    for (int jj=0;jj<16;jj++) acc[jj] = fmaf(v, w[jj], acc[jj]);
  }
  for (int ci=0; ci<32; ci++){
    float v = uls[ci][lane];
    const float* w = wT + 5120 + (96+ci)*64 + kk*16;
    #pragma unroll
    for (int jj=0;jj<16;jj++) acc[jj] = fmaf(v, w[jj], acc[jj]);
  }
  float* op = outp + (size_t)b*64*HWFn + tile*64 + lane;
  #pragma unroll
  for (int jj=0;jj<16;jj++)
    op[(size_t)(kk*16+jj)*HWFn] = acc[jj];
}

// ---------- MFMA 3x3 conv: Cout=64, one output row per WG ----------
constexpr int XST = 72;
__global__ __launch_bounds__(256) void k_mconv(
    const float* __restrict__ in, const float* __restrict__ in2,
    const unsigned short* __restrict__ wpk, const float* __restrict__ bias,
    const float* __restrict__ res, float* __restrict__ out,
    int nblk, int dl, int leaky){
  __shared__ short lds[3*134*XST];
  int b = blockIdx.x >> 7, y = blockIdx.x & 127;
  int tid = threadIdx.x;
  int wv = tid >> 6, lane = tid & 63;
  int nq = lane >> 4, nr = lane & 15;
  float4v acc[4][2];
  #pragma unroll
  for (int mt=0; mt<4; mt++)
    #pragma unroll
    for (int nt=0; nt<2; nt++) acc[mt][nt] = (float4v){0.f,0.f,0.f,0.f};

  for (int blk=0; blk<nblk; blk++){
    const float* src = blk ? in2 : in;
    __syncthreads();
    for (int e = tid; e < 3*16*32; e += 256){
      int dy = e >> 9;
      int r  = e & 511;
      int c4 = r >> 5;
      int xx = (r & 31) << 2;          // 0..124
      int yy = y + (dy-1)*dl;
      float4 v0, v1, v2, v3;
      if (yy >= 0 && yy < Hn){
        const float* sp2 = src + (((size_t)b*64 + c4*4)*Hn + yy)*Wn + xx;
        v0 = *(const float4*)(sp2);
        v1 = *(const float4*)(sp2 + HWn);
        v2 = *(const float4*)(sp2 + 2*HWn);
        v3 = *(const float4*)(sp2 + 3*HWn);
      } else {
        v0 = v1 = v2 = v3 = make_float4(0.f,0.f,0.f,0.f);
      }
      #pragma unroll
      for (int j=0; j<4; j++){
        float f0 = (&v0.x)[j], f1 = (&v1.x)[j], f2 = (&v2.x)[j], f3 = (&v3.x)[j];
        unsigned p0 = ((unsigned)(unsigned short)f2bf(f0)) | (((unsigned)(unsigned short)f2bf(f1)) << 16);
        unsigned p1 = ((unsigned)(unsigned short)f2bf(f2)) | (((unsigned)(unsigned short)f2bf(f3)) << 16);
        *(uint2*)&lds[(dy*134 + xx + 3 + j)*XST + c4*4] = make_uint2(p0, p1);
      }
    }
    for (int e = tid; e < 3*16*6; e += 256){
      int dy = e / 96; int r = e - dy*96;
      int c4 = r / 6;  int k = r - c4*6;
      int x = (k < 3) ? k : 128 + k;
      *(uint2*)&lds[(dy*134 + x)*XST + c4*4] = make_uint2(0u, 0u);
    }
    __syncthreads();
    const unsigned short* wb = wpk + (size_t)blk*36864;
    #pragma unroll 3
    for (int tap=0; tap<9; tap++){
      int dy = tap/3, dx = tap - (tap/3)*3;
      #pragma unroll
      for (int ks=0; ks<2; ks++){
        short8 a[4];
        #pragma unroll
        for (int mt=0; mt<4; mt++)
          a[mt] = *(const short8*)(wb + (((size_t)(tap*2+ks)*4+mt)<<9) + ((size_t)lane<<3));
        #pragma unroll
        for (int nt=0; nt<2; nt++){
          int x = wv*32 + nt*16 + nr + (dx-1)*dl + 3;
          short8 bf = *(const short8*)&lds[(dy*134 + x)*XST + ks*32 + nq*8];
          #pragma unroll
          for (int mt=0; mt<4; mt++)
            acc[mt][nt] = __builtin_amdgcn_mfma_f32_16x16x32_bf16(a[mt], bf, acc[mt][nt], 0, 0, 0);
        }
      }
    }
  }
  #pragma unroll
  for (int mt=0; mt<4; mt++)
  #pragma unroll
  for (int nt=0; nt<2; nt++){
    int x = wv*32 + nt*16 + nr;
    #pragma unroll
    for (int r2=0; r2<4; r2++){
      int co = mt*16 + nq*4 + r2;
      float a = acc[mt][nt][r2] + (bias ? bias[co] : 0.f);
      if (leaky) a = (a >= 0.f) ? a : 0.01f*a;
      size_t idx = (((size_t)b*64 + co)*Hn + y)*Wn + x;
      if (res) a += res[idx];
      out[idx] = a;
    }
  }
}

// ---------- fused depthwise 3x3 + pointwise 1x1 (Cin=64) via MFMA ----------
template<int MT>
__global__ __launch_bounds__(256) void k_dwpw(
    const float* __restrict__ in, const float* __restrict__ dww, const float* __restrict__ dwb,
    const unsigned short* __restrict__ pwpk, const float* __restrict__ pwb,
    float* __restrict__ out, int Cout, size_t outb, int post){
  __shared__ short tb[128*72];       // dw output [x][ci] bf16
  __shared__ float wsm[640];         // dw weights 64*9 + bias 64
  int b = blockIdx.x >> 7, y = blockIdx.x & 127;
  int tid = threadIdx.x;
  for (int i = tid; i < 640; i += 256)
    wsm[i] = (i < 576) ? dww[i] : (dwb ? dwb[i-576] : 0.f);
  __syncthreads();
  for (int e = tid; e < 2048; e += 256){
    int ci = e >> 5;
    int xx = (e & 31) << 2;            // 0..124
    const float* ip = in + ((size_t)b*64 + ci)*HWn;
    const float* wp = wsm + ci*9;
    float4 a0 = make_float4(0.f,0.f,0.f,0.f), a1 = a0, a2 = a0;
    float L0=0.f,L1=0.f,L2=0.f,R0=0.f,R1=0.f,R2=0.f;
    if (y > 0){
      const float* r = ip + (y-1)*Wn;
      a0 = *(const float4*)(r + xx);
      if (xx) L0 = r[xx-1];
      if (xx < 124) R0 = r[xx+4];
    }
    {
      const float* r = ip + y*Wn;
      a1 = *(const float4*)(r + xx);
      if (xx) L1 = r[xx-1];
      if (xx < 124) R1 = r[xx+4];
    }
    if (y < Hn-1){
      const float* r = ip + (y+1)*Wn;
      a2 = *(const float4*)(r + xx);
      if (xx) L2 = r[xx-1];
      if (xx < 124) R2 = r[xx+4];
    }
    float bb = wsm[576+ci];
    float o0=bb,o1=bb,o2=bb,o3=bb;
    float w0=wp[0],w1=wp[1],w2=wp[2];
    o0 = fmaf(w0,L0,  fmaf(w1,a0.x, fmaf(w2,a0.y, o0)));
    o1 = fmaf(w0,a0.x,fmaf(w1,a0.y, fmaf(w2,a0.z, o1)));
    o2 = fmaf(w0,a0.y,fmaf(w1,a0.z, fmaf(w2,a0.w, o2)));
    o3 = fmaf(w0,a0.z,fmaf(w1,a0.w, fmaf(w2,R0,   o3)));
    w0=wp[3];w1=wp[4];w2=wp[5];
    o0 = fmaf(w0,L1,  fmaf(w1,a1.x, fmaf(w2,a1.y, o0)));
    o1 = fmaf(w0,a1.x,fmaf(w1,a1.y, fmaf(w2,a1.z, o1)));
    o2 = fmaf(w0,a1.y,fmaf(w1,a1.z, fmaf(w2,a1.w, o2)));
    o3 = fmaf(w0,a1.z,fmaf(w1,a1.w, fmaf(w2,R1,   o3)));
    w0=wp[6];w1=wp[7];w2=wp[8];
    o0 = fmaf(w0,L2,  fmaf(w1,a2.x, fmaf(w2,a2.y, o0)));
    o1 = fmaf(w0,a2.x,fmaf(w1,a2.y, fmaf(w2,a2.z, o1)));
    o2 = fmaf(w0,a2.y,fmaf(w1,a2.z, fmaf(w2,a2.w, o2)));
    o3 = fmaf(w0,a2.z,fmaf(w1,a2.w, fmaf(w2,R2,   o3)));
    short* d = &tb[xx*72 + ci];
    d[0]   = f2bf(o0);
    d[72]  = f2bf(o1);
    d[144] = f2bf(o2);
    d[216] = f2bf(o3);
  }
  __syncthreads();
  int wv = tid>>6, lane = tid&63, nq = lane>>4, nr = lane&15;
  float4v acc[MT][2];
  #pragma unroll
  for (int mt=0; mt<MT; mt++)
    #pragma unroll
    for (int nt=0; nt<2; nt++) acc[mt][nt] = (float4v){0.f,0.f,0.f,0.f};
  #pragma unroll
  for (int ks=0; ks<2; ks++){
    short8 a[MT];
    #pragma unroll
    for (int mt=0; mt<MT; mt++)
      a[mt] = *(const short8*)(pwpk + ((ks*MT+mt)<<9) + (lane<<3));
    #pragma unroll
    for (int nt=0; nt<2; nt++){
      int x = wv*32 + nt*16 + nr;
      short8 bf = *(const short8*)&tb[x*72 + ks*32 + nq*8];
      #pragma unroll
      for (int mt=0; mt<MT; mt++)
        acc[mt][nt] = __builtin_amdgcn_mfma_f32_16x16x32_bf16(a[mt], bf, acc[mt][nt], 0, 0, 0);
    }
  }
  #pragma unroll
  for (int mt=0; mt<MT; mt++)
  #pragma unroll
  for (int nt=0; nt<2; nt++){
    int x = wv*32 + nt*16 + nr;
    #pragma unroll
    for (int r2=0; r2<4; r2++){
      int co = mt*16 + nq*4 + r2;
      if (co < Cout){
        float a = acc[mt][nt][r2] + (pwb ? pwb[co] : 0.f);
        if (post == 1) a = fminf(fmaxf(a, -1.f), 1.f);
        else if (post == 2) a = a*fminf(fmaxf(a+3.f, 0.f), 6.f)*(1.f/6.f);
        out[(size_t)b*outb + (size_t)co*HWn + y*Wn + x] = a;
      }
    }
  }
}

// ---------- fused deformable dw 3x3 + pointwise 1x1 (64 -> Cout<=16) ----------
__global__ __launch_bounds__(512) void k_defpw(
    const float* __restrict__ xg, const float* __restrict__ off, const float* __restrict__ dcnw,
    const unsigned short* __restrict__ pwpk, float* __restrict__ out,
    int Cout, size_t outb, int post){
  __shared__ unsigned short xs[5*64*130];   // [tr][ci][c] bf16 (83.2 KB)
  __shared__ short tb[128*72];
  __shared__ float wsm[576];
  int b = blockIdx.x >> 7, y = blockIdx.x & 127;
  int tid = threadIdx.x;
  int px = tid & 127, sub = tid >> 7;       // 4 threads per pixel
  for (int i = tid; i < 576; i += 512) wsm[i] = dcnw[i];
  for (int e = tid; e < 10240; e += 512){   // 5*64*32 float4 units
    int tr = e >> 11;
    int r  = e & 2047;
    int ci = r >> 5;
    int xx = (r & 31) << 2;
    int gy = min(max(y - 2 + tr, 0), Hn-1);
    float4 v = *(const float4*)&xg[(((size_t)b*64 + ci)*Hn + gy)*Wn + xx];
    unsigned short* d = &xs[(tr*64 + ci)*130 + xx];
    d[0] = (unsigned short)f2bf(v.x);
    d[1] = (unsigned short)f2bf(v.y);
    d[2] = (unsigned short)f2bf(v.z);
    d[3] = (unsigned short)f2bf(v.w);
  }
  const float* op = off + (size_t)b*18*HWn + y*Wn + px;
  int t0[9], t1[9], c0[9], c1[9];
  float w00[9], w01[9], w10[9], w11[9];
  #pragma unroll
  for (int k=0; k<9; k++){
    int ky = k/3 - 1, kx = k - (k/3)*3 - 1;
    float oy = op[(size_t)(2*k)*HWn];
    float ox = op[(size_t)(2*k+1)*HWn];
    float py = (float)(y + ky) + oy;
    float pxx = (float)(px + kx) + ox;
    float fy = floorf(py), fx = floorf(pxx);
    float wy = py - fy, wx = pxx - fx;
    int y0 = (int)fy, x0 = (int)fx;
    float vy0 = (y0 >= 0 && y0 < Hn) ? 1.f : 0.f;
    float vy1 = (y0+1 >= 0 && y0+1 < Hn) ? 1.f : 0.f;
    float vx0 = (x0 >= 0 && x0 < Wn) ? 1.f : 0.f;
    float vx1 = (x0+1 >= 0 && x0+1 < Wn) ? 1.f : 0.f;
    w00[k] = (1.f-wy)*(1.f-wx)*vy0*vx0;
    w01[k] = (1.f-wy)*wx*vy0*vx1;
    w10[k] = wy*(1.f-wx)*vy1*vx0;
    w11[k] = wy*wx*vy1*vx1;
    t0[k] = min(max(min(max(y0,   0), Hn-1) - (y-2), 0), 4);
    t1[k] = min(max(min(max(y0+1, 0), Hn-1) - (y-2), 0), 4);
    c0[k] = min(max(x0,   0), Wn-1);
    c1[k] = min(max(x0+1, 0), Wn-1);
  }
  __syncthreads();
  for (int ci = sub; ci < 64; ci += 4){
    float acc = 0.f;
    #pragma unroll
    for (int k=0; k<9; k++){
      const unsigned short* b0 = &xs[(t0[k]*64 + ci)*130];
      const unsigned short* b1 = &xs[(t1[k]*64 + ci)*130];
      float v = w00[k]*bf2f(b0[c0[k]]) + w01[k]*bf2f(b0[c1[k]])
              + w10[k]*bf2f(b1[c0[k]]) + w11[k]*bf2f(b1[c1[k]]);
      acc = fmaf(v, wsm[ci*9 + k], acc);
    }
    tb[px*72 + ci] = f2bf(acc);
  }
  __syncthreads();
  int wv = tid>>6, lane = tid&63, nq = lane>>4, nr = lane&15;
  float4v acc = (float4v){0.f,0.f,0.f,0.f};
  int x = wv*16 + nr;
  #pragma unroll
  for (int ks=0; ks<2; ks++){
    short8 a = *(const short8*)(pwpk + (ks<<9) + (lane<<3));
    short8 bf = *(const short8*)&tb[x*72 + ks*32 + nq*8];
    acc = __builtin_amdgcn_mfma_f32_16x16x32_bf16(a, bf, acc, 0, 0, 0);
  }
  #pragma unroll
  for (int r2=0; r2<4; r2++){
    int co = nq*4 + r2;
    if (co < Cout){
      float a = acc[r2];
      if (post == 2) a = a*fminf(fmaxf(a+3.f, 0.f), 6.f)*(1.f/6.f);
      out[(size_t)b*outb + (size_t)co*HWn + y*Wn + x] = a;
    }
  }
}

// ---------- depthwise 3x3, pad 1 (phase-1, 3ch) ----------
__global__ void k_dw3x3(const float* __restrict__ in, const float* __restrict__ w,
                        const float* __restrict__ bias, float* __restrict__ out, int C){
  int bc = blockIdx.x; int y = blockIdx.y; int x = threadIdx.x;
  int c = bc % C;
  const float* ip = in + (size_t)bc*HWn;
  const float* wp = w + c*9;
  float acc = bias ? bias[c] : 0.f;
  #pragma unroll
  for (int ky=0; ky<3; ky++){
    int yy = y + ky - 1; if (yy < 0 || yy >= Hn) continue;
    #pragma unroll
    for (int kx=0; kx<3; kx++){
      int xx = x + kx - 1; if (xx < 0 || xx >= Wn) continue;
      acc = fmaf(ip[yy*Wn+xx], wp[ky*3+kx], acc);
    }
  }
  out[(size_t)bc*HWn + y*Wn + x] = acc;
}

// ---------- pointwise 1x1, register-tiled (phase-1 only) ----------
template<int CT>
__global__ void k_pwt(const float* __restrict__ in, const float* __restrict__ wg,
                      const float* __restrict__ bias, const float* __restrict__ bng,
                      const float* __restrict__ bnb, float* __restrict__ out,
                      int Cin, int Cout, int npix, int inb, int outb, int post, float slope){
  extern __shared__ float wsm[];
  int nt = (Cout + CT - 1)/CT;
  int b = blockIdx.x / nt, t = blockIdx.x - b*nt;
  int co0 = t*CT;
  for (int i = threadIdx.x; i < CT*Cin; i += 256){
    int co = i / Cin;
    wsm[i] = (co0 + co < Cout) ? wg[(size_t)(co0+co)*Cin + (i - co*Cin)] : 0.f;
  }
  __syncthreads();
  int p = blockIdx.y*256 + threadIdx.x;
  if (p >= npix) return;
  const float* ip = in + (size_t)b*inb + p;
  float acc[CT];
  #pragma unroll
  for (int j=0; j<CT; j++) acc[j] = 0.f;
  for (int ci=0; ci<Cin; ci++){
    float v = ip[(size_t)ci*npix];
    #pragma unroll
    for (int j=0; j<CT; j++) acc[j] = fmaf(v, wsm[j*Cin+ci], acc[j]);
  }
  #pragma unroll
  for (int j=0; j<CT; j++){
    int co = co0 + j;
    if (co < Cout){
      float a = acc[j] + (bias ? bias[co] : 0.f);
      if (bng) a = a*(bng[co]*BN_SCALE) + bnb[co];
      if (post == 1) a = fminf(fmaxf(a, -1.f), 1.f);
      else if (post == 2) a = a*fminf(fmaxf(a+3.f, 0.f), 6.f)*(1.f/6.f);
      else if (post == 3) a = (a >= 0.f) ? a : a*slope;
      out[(size_t)b*outb + (size_t)co*npix + p] = a;
    }
  }
}

// ---------- deformable depthwise 3x3 (phase-1, 3ch) ----------
__global__ void k_deform(const float* __restrict__ x, const float* __restrict__ off,
                         const float* __restrict__ w, float* __restrict__ out, int C){
  int bc = blockIdx.x; int b = bc / C; int c = bc - b*C;
  int y = blockIdx.y; int x0 = threadIdx.x;
  const float* xp = x + (size_t)bc*HWn;
  const float* op = off + (size_t)b*18*HWn + y*Wn + x0;
  const float* wp = w + c*9;
  float acc = 0.f;
  #pragma unroll
  for (int k=0; k<9; k++){
    int ky = k/3 - 1, kx = k - (k/3)*3 - 1;
    float oy = op[(size_t)(2*k)*HWn];
    float ox = op[(size_t)(2*k+1)*HWn];
    float py = (float)y + (float)ky + oy;
    float px = (float)x0 + (float)kx + ox;
    float fy = floorf(py), fx = floorf(px);
    float wy = py - fy, wx = px - fx;
    int y0 = (int)fy, xx0 = (int)fx;
    float val = 0.f;
    #pragma unroll
    for (int dy=0; dy<2; dy++){
      int iy = y0 + dy; if (iy < 0 || iy >= Hn) continue;
      float wyv = dy ? wy : (1.f - wy);
      #pragma unroll
      for (int dx=0; dx<2; dx++){
        int ix = xx0 + dx; if (ix < 0 || ix >= Wn) continue;
        float wxv = dx ? wx : (1.f - wx);
        val = fmaf(xp[iy*Wn+ix], wyv*wxv, val);
      }
    }
    acc = fmaf(val, wp[k], acc);
  }
  out[(size_t)bc*HWn + y*Wn + x0] = acc;
}

// ---------- small direct conv (final 6->3) ----------
__global__ void k_conv3x3s(const float* __restrict__ in, const float* __restrict__ wgt,
                           const float* __restrict__ bias, const float* __restrict__ res,
                           float* __restrict__ out, int Cin, int Cout){
  int g = blockIdx.x;
  int b = g / Cout; int o0 = g - b*Cout;
  int y = blockIdx.y, x = threadIdx.x;
  float acc = bias ? bias[o0] : 0.f;
  for (int ci=0; ci<Cin; ci++){
    const float* iip = in + ((size_t)b*Cin + ci)*HWn;
    const float* wp = wgt + ((size_t)o0*Cin + ci)*9;
    #pragma unroll
    for (int ky=0; ky<3; ky++){
      int yy = y + ky - 1; if (yy < 0 || yy >= Hn) continue;
      #pragma unroll
      for (int kx=0; kx<3; kx++){
        int xx = x + kx - 1; if (xx < 0 || xx >= Wn) continue;
        acc = fmaf(iip[yy*Wn+xx], wp[ky*3+kx], acc);
      }
    }
  }
  size_t idx = ((size_t)b*Cout + o0)*HWn + y*Wn + x;
  if (res) acc += res[idx];
  out[idx] = acc;
}

// ---------- fused cross-attention: one WG per (b,h), 256 threads ----------
// LDS rows padded to 132 (mult of 4) so q/k/v rows admit aligned float4
// (ds_read_b128) reads; QK tiles over i, PV reads vs rows as 2x float4.
// f32 accumulation order (i, d ascending) identical to scalar version.
__global__ __launch_bounds__(256) void k_attn(
    const float* __restrict__ q, const float* __restrict__ k,
    const float* __restrict__ v, float* __restrict__ o){
  __shared__ float qs[64][132];
  __shared__ float ks[64][132];
  __shared__ float vs[64][132];
  __shared__ float ps[64][66];
  int bh = blockIdx.x; int b = bh >> 7, h = bh & 127;
  size_t base = ((size_t)b*64*128 + h)*128;
  int tid = threadIdx.x;
  for (int e = tid; e < 8192; e += 256){
    int c = e >> 7, w = e & 127;
    size_t g = base + (size_t)c*HWn + w;
    qs[c][w] = q[g]; ks[c][w] = k[g]; vs[c][w] = v[g];
  }
  __syncthreads();
  {
    int c0 = (tid >> 4) << 2, d0 = (tid & 15) << 2;
    float acc[4][4];
    #pragma unroll
    for (int a=0; a<4; a++)
      #pragma unroll
      for (int bb=0; bb<4; bb++) acc[a][bb] = 0.f;
    for (int i4=0; i4<32; i4++){
      float4 qv[4], kv[4];
      #pragma unroll
      for (int a=0; a<4; a++)  qv[a]  = *(const float4*)&qs[c0+a][i4*4];
      #pragma unroll
      for (int bb=0; bb<4; bb++) kv[bb] = *(const float4*)&ks[d0+bb][i4*4];
      #pragma unroll
      for (int a=0; a<4; a++)
        #pragma unroll
        for (int bb=0; bb<4; bb++){
          acc[a][bb] = fmaf(qv[a].x, kv[bb].x, acc[a][bb]);
          acc[a][bb] = fmaf(qv[a].y, kv[bb].y, acc[a][bb]);
          acc[a][bb] = fmaf(qv[a].z, kv[bb].z, acc[a][bb]);
          acc[a][bb] = fmaf(qv[a].w, kv[bb].w, acc[a][bb]);
        }
    }
    #pragma unroll
    for (int a=0; a<4; a++)
      #pragma unroll
      for (int bb=0; bb<4; bb++)
        ps[c0+a][d0+bb] = acc[a][bb] * 0.35355339059327373f;
  }
  __syncthreads();
  {
    int wv = tid >> 6, lane = tid & 63;
    for (int it=0; it<16; it++){
      int row = wv*16 + it;
      float vv = ps[row][lane];
      float m = vv;
      #pragma unroll
      for (int off=32; off; off>>=1) m = fmaxf(m, __shfl_xor(m, off));
      float e = expf(vv - m);
      float s = e;
      #pragma unroll
      for (int off=32; off; off>>=1) s += __shfl_xor(s, off);
      ps[row][lane] = e / s;
    }
  }
  __syncthreads();
  {
    int c0 = (tid >> 4) << 2, w0 = (tid & 15) << 3;
    float acc[4][8];
    #pragma unroll
    for (int a=0; a<4; a++)
      #pragma unroll
      for (int j=0; j<8; j++) acc[a][j] = 0.f;
    for (int d=0; d<64; d++){
      float pv[4];
      float4 v0 = *(const float4*)&vs[d][w0];
      float4 v1 = *(const float4*)&vs[d][w0+4];
      #pragma unroll
      for (int a=0; a<4; a++) pv[a] = ps[c0+a][d];
      #pragma unroll
      for (int a=0; a<4; a++){
        acc[a][0] = fmaf(pv[a], v0.x, acc[a][0]);
        acc[a][1] = fmaf(pv[a], v0.y, acc[a][1]);
        acc[a][2] = fmaf(pv[a], v0.z, acc[a][2]);
        acc[a][3] = fmaf(pv[a], v0.w, acc[a][3]);
        acc[a][4] = fmaf(pv[a], v1.x, acc[a][4]);
        acc[a][5] = fmaf(pv[a], v1.y, acc[a][5]);
        acc[a][6] = fmaf(pv[a], v1.z, acc[a][6]);
        acc[a][7] = fmaf(pv[a], v1.w, acc[a][7]);
      }
    }
    #pragma unroll
    for (int a=0; a<4; a++)
      #pragma unroll
      for (int j=0; j<8; j++)
        o[base + (size_t)(c0+a)*HWn + w0 + j] = acc[a][j];
  }
}

// ============ wave-level 128-pt FFT (no barriers, register-resident) ============
__device__ __forceinline__ float2 cmul(float2 a, float2 b){
  return make_float2(a.x*b.x - a.y*b.y, a.x*b.y + a.y*b.x);
}

// two interleaved 128-pt FFTs: (z[0],z[1]) and (z[2],z[3]) — 4 chains in flight
__device__ __forceinline__ void wfft4(float2* z, const float2* twl, int l){
  #pragma unroll
  for (int q=0; q<2; q++){
    float dx = z[2*q].x - z[2*q+1].x, dy = z[2*q].y - z[2*q+1].y;
    z[2*q].x += z[2*q+1].x; z[2*q].y += z[2*q+1].y;
    z[2*q+1] = cmul(make_float2(dx, dy), twl[6]);
  }
  #pragma unroll
  for (int s = 5; s >= 0; --s){
    int h = 1 << s;
    bool up = (l & h) != 0;
    float2 w = twl[s];
    #pragma unroll
    for (int q=0; q<4; q++){
      float ox = __shfl_xor(z[q].x, h), oy = __shfl_xor(z[q].y, h);
      float sx = up ? ox - z[q].x : z[q].x + ox;
      float sy = up ? oy - z[q].y : z[q].y + oy;
      float2 t = cmul(make_float2(sx, sy), w);
      z[q].x = up ? t.x : sx;  z[q].y = up ? t.y : sy;
    }
  }
}

__device__ __forceinline__ void wreorder(float2 z0, float2 z1, float2& n0, float2& n1, int l){
  int a = (int)(__brev((unsigned)(l >> 1)) >> 26);
  float p0x = __shfl(z0.x, a),   p0y = __shfl(z0.y, a);
  float p1x = __shfl(z1.x, a),   p1y = __shfl(z1.y, a);
  float q0x = __shfl(z0.x, a+1), q0y = __shfl(z0.y, a+1);
  float q1x = __shfl(z1.x, a+1), q1y = __shfl(z1.y, a+1);
  bool odd = (l & 1) != 0;
  n0 = odd ? make_float2(p1x, p1y) : make_float2(p0x, p0y);
  n1 = odd ? make_float2(q1x, q1y) : make_float2(q0x, q0y);
}

// ---------- fused rfft2 + mag/pha: 512 threads (8 waves) for TLP ----------
__global__ __launch_bounds__(512) void k_fft2(
    const float* __restrict__ x, float* __restrict__ mag, float* __restrict__ pha){
  __shared__ float spr[8320];
  __shared__ float spi[8320];
  int img = blockIdx.x;
  int tid = threadIdx.x;
  int wv = tid >> 6, l = tid & 63;
  float2 twl[7];
  #pragma unroll
  for (int s = 0; s < 7; ++s){
    int jh = (l & ((1 << s) - 1)) << (6 - s);
    float sv, cv; sincosf(-TWOPI * (float)jh * (1.f/128.f), &sv, &cv);
    twl[s] = make_float2(cv, sv);
  }
  const float* xp = x + (size_t)img*HWn;
  for (int f = wv; f < 32; f += 8){
    int fB = f + 32;
    float2 z[4];
    {
      const float* a0 = xp + (2*f)*Wn;  const float* a1 = a0 + Wn;
      const float* b0 = xp + (2*fB)*Wn; const float* b1 = b0 + Wn;
      z[0] = make_float2(a0[l],      a1[l]);
      z[1] = make_float2(a0[64 + l], a1[64 + l]);
      z[2] = make_float2(b0[l],      b1[l]);
      z[3] = make_float2(b0[64 + l], b1[64 + l]);
    }
    wfft4(z, twl, l);
    #pragma unroll
    for (int q=0; q<2; q++){
      int ff = q ? fB : f;
      float2 n0, n1; wreorder(z[2*q], z[2*q+1], n0, n1, l);
      float zhx = __shfl(n1.x, (64 - l) & 63);
      float zhy = __shfl(n1.y, (64 - l) & 63);
      float2 Zn = (l == 0) ? n0 : make_float2(zhx, zhy);
      int iA = (2*ff)*65 + l, iB = (2*ff+1)*65 + l;
      spr[iA] = 0.5f*(n0.x + Zn.x);  spi[iA] = 0.5f*(n0.y - Zn.y);
      spr[iB] = 0.5f*(n0.y + Zn.y);  spi[iB] = 0.5f*(Zn.x - n0.x);
      if (l == 0){
        spr[(2*ff)*65 + 64]   = n1.x;  spi[(2*ff)*65 + 64]   = 0.f;
        spr[(2*ff+1)*65 + 64] = n1.y;  spi[(2*ff+1)*65 + 64] = 0.f;
      }
    }
  }
  __syncthreads();
  for (int c = wv; c < 33; c += 8){
    int cB = c + 33;
    bool h2 = cB < 65;
    int cB_s = h2 ? cB : c;
    float2 z[4];
    z[0] = make_float2(spr[l*65 + c],        spi[l*65 + c]);
    z[1] = make_float2(spr[(64 + l)*65 + c], spi[(64 + l)*65 + c]);
    z[2] = make_float2(spr[l*65 + cB_s],        spi[l*65 + cB_s]);
    z[3] = make_float2(spr[(64 + l)*65 + cB_s], spi[(64 + l)*65 + cB_s]);
    wfft4(z, twl, l);
    {
      float2 n0, n1; wreorder(z[0], z[1], n0, n1, l);
      spr[l*65 + c]        = sqrtf(n0.x*n0.x + n0.y*n0.y);
      spi[l*65 + c]        = atan2f(n0.y, n0.x);
      spr[(64 + l)*65 + c] = sqrtf(n1.x*n1.x + n1.y*n1.y);
      spi[(64 + l)*65 + c] = atan2f(n1.y, n1.x);
    }
    if (h2){
      float2 n0, n1; wreorder(z[2], z[3], n0, n1, l);
      spr[l*65 + cB]        = sqrtf(n0.x*n0.x + n0.y*n0.y);
      spi[l*65 + cB]        = atan2f(n0.y, n0.x);
      spr[(64 + l)*65 + cB] = sqrtf(n1.x*n1.x + n1.y*n1.y);
      spi[(64 + l)*65 + cB] = atan2f(n1.y, n1.x);
    }
  }
  __syncthreads();
  float* mp = mag + (size_t)img*HWFn;
  float* pp = pha + (size_t)img*HWFn;
  for (int i = tid; i < 8320; i += 512){
    mp[i] = spr[i]; pp[i] = spi[i];
  }
}

// ---------- fused irfft2 + residual add: 512 threads ----------
__global__ __launch_bounds__(512) void k_ifft2(
    const float* __restrict__ mo, const float* __restrict__ po,
    const float* __restrict__ hsrc, float* __restrict__ outp){
  __shared__ float spr[8320];
  __shared__ float spi[8320];
  int img = blockIdx.x;
  int tid = threadIdx.x;
  int wv = tid >> 6, l = tid & 63;
  float2 twl[7];
  #pragma unroll
  for (int s = 0; s < 7; ++s){
    int jh = (l & ((1 << s) - 1)) << (6 - s);
    float sv, cv; sincosf(TWOPI * (float)jh * (1.f/128.f), &sv, &cv);
    twl[s] = make_float2(cv, sv);
  }
  const float* mp = mo + (size_t)img*HWFn;
  const float* pp = po + (size_t)img*HWFn;
  for (int i = tid; i < 8320; i += 512){
    float m = mp[i], p = pp[i];
    float sv, cv; sincosf(p, &sv, &cv);
    spr[i] = m*cv; spi[i] = m*sv;
  }
  __syncthreads();
  for (int c = wv; c < 33; c += 8){
    int cB = c + 33;
    bool h2 = cB < 65;
    int cB_s = h2 ? cB : c;
    float2 z[4];
    z[0] = make_float2(spr[l*65 + c],        spi[l*65 + c]);
    z[1] = make_float2(spr[(64 + l)*65 + c], spi[(64 + l)*65 + c]);
    z[2] = make_float2(spr[l*65 + cB_s],        spi[l*65 + cB_s]);
    z[3] = make_float2(spr[(64 + l)*65 + cB_s], spi[(64 + l)*65 + cB_s]);
    wfft4(z, twl, l);
    {
      float2 n0, n1; wreorder(z[0], z[1], n0, n1, l);
      spr[l*65 + c] = n0.x;        spi[l*65 + c] = n0.y;
      spr[(64 + l)*65 + c] = n1.x; spi[(64 + l)*65 + c] = n1.y;
    }
    if (h2){
      float2 n0, n1; wreorder(z[2], z[3], n0, n1, l);
      spr[l*65 + cB] = n0.x;        spi[l*65 + cB] = n0.y;
      spr[(64 + l)*65 + cB] = n1.x; spi[(64 + l)*65 + cB] = n1.y;
    }
  }
  __syncthreads();
  const float scl = 1.f/16384.f;
  for (int f = wv; f < 32; f += 8){
    int fB = f + 32;
    float2 z[4];
    #pragma unroll
    for (int q=0; q<2; q++){
      int ff = q ? fB : f;
      int iA = (2*ff)*65 + l, iB = (2*ff+1)*65 + l;
      float2 A  = make_float2(spr[iA], spi[iA]);
      float2 Bv = make_float2(spr[iB], spi[iB]);
      if (l == 0){ A.y = 0.f; Bv.y = 0.f; }
      z[2*q] = make_float2(A.x - Bv.y, A.y + Bv.x);
      int lm = 64 - l;
      float2 Am = make_float2(spr[(2*ff)*65 + lm],   spi[(2*ff)*65 + lm]);
      float2 Bm = make_float2(spr[(2*ff+1)*65 + lm], spi[(2*ff+1)*65 + lm]);
      z[2*q+1] = (l == 0) ? make_float2(Am.x, Bm.x)
                          : make_float2(Am.x + Bm.y, Bm.x - Am.y);
    }
    wfft4(z, twl, l);
    #pragma unroll
    for (int q=0; q<2; q++){
      int ff = q ? fB : f;
      float2 n0, n1; wreorder(z[2*q], z[2*q+1], n0, n1, l);
      size_t g0 = (size_t)img*HWn + (size_t)(2*ff)*Wn + l;
      size_t g1 = g0 + Wn;
      outp[g0]      = n0.x*scl + hsrc[g0];
      outp[g0 + 64] = n1.x*scl + hsrc[g0 + 64];
      outp[g1]      = n0.y*scl + hsrc[g1];
      outp[g1 + 64] = n1.y*scl + hsrc[g1 + 64];
    }
  }
}

} // namespace

extern "C" void kernel_launch(void* const* d_in, const int* in_sizes, int n_in,
                              void* d_out, int out_size, void* d_ws, size_t ws_size,
                              hipStream_t stream){
  const float *xf   =(const float*)d_in[0],  *chodw=(const float*)d_in[1],
              *chopw=(const float*)d_in[2],  *chdcn=(const float*)d_in[3],
              *chpw =(const float*)d_in[4],  *ctodw=(const float*)d_in[5],
              *ctopw=(const float*)d_in[6],  *ctdcn=(const float*)d_in[7],
              *ctpw =(const float*)d_in[8],  *dbw  =(const float*)d_in[9],
              *dbb  =(const float*)d_in[10], *cadw =(const float*)d_in[11],
              *cadb =(const float*)d_in[12], *capw =(const float*)d_in[13],
              *capb =(const float*)d_in[14], *hhw  =(const float*)d_in[15],
              *hhb  =(const float*)d_in[16], *fd1w =(const float*)d_in[17],
              *fd2w =(const float*)d_in[18], *fd1g =(const float*)d_in[19],
              *fd1bt=(const float*)d_in[20], *fd2g =(const float*)d_in[21],
              *fd2bt=(const float*)d_in[22], *fcw  =(const float*)d_in[23],
              *cw   =(const float*)d_in[24], *cb   =(const float*)d_in[25];

  constexpr size_t M = 1048576;            // one batch x 64ch x HW (floats)
  float* ws = (float*)d_ws;
  float* h     = ws;                       // 12*M
  float* fftHL = ws + 12*M;                // 4*M
  float* cat6  = ws + 16*M;                // 1,179,648
  unsigned short* wpkDB = (unsigned short*)(cat6 + 1179648);
  unsigned short* wpkHH = wpkDB + 552960;
  float* wfdc = (float*)(wpkHH + 73728);   // 26624 floats (2 branches x 13312)
  float* P = cat6 + 1179648 + 313344 + 26624;   // pool

  const int NB = (ws_size >= 266018816ull) ? 4 : (ws_size >= 173850624ull) ? 2 : 1;
  const size_t S = (size_t)NB*M;
  float* kb  = P;        float* vb  = P + S;   float* qb  = P + 2*S;
  float* qsl = P + 3*S;  // packed pw weights live here (written after phase 2)
  float* aA  = P + 4*S;  float* aB  = P + 5*S;
  float* aC  = P + 6*S;  float* hh1 = P + 7*S; float* sA  = P + 8*S;
  float* sB  = P + 9*S;  float* dbuf= P + 10*S;
  float* X   = P + 11*S;
  unsigned short* pwpkCA = (unsigned short*)qsl;      // 6*4096
  unsigned short* pwpkTO = pwpkCA + 24576;            // 2048
  unsigned short* pwpkTP = pwpkTO + 2048;             // 1024
  // phase-1 aliases
  float* dwb3 = P; float* offb12 = P + 589824; float* yb3 = P + 4128768;

  float* out = (float*)d_out;
  float* out0 = out;
  float* out1 = out + 589824;
  float* out2 = out + 589824 + 6389760;

  auto PW = [&](const float* in, const float* wg, const float* bi, const float* g, const float* bt,
                float* o, int B, int Ci, int Co, int npix, int inb, int outb, int post, float slope){
    int py = (npix + 255)/256;
    if (Co > 32){
      k_pwt<32><<<dim3(B*2, py), 256, 32*Ci*4, stream>>>(in, wg, bi, g, bt, o, Ci, Co, npix, inb, outb, post, slope);
    } else if (Co > 18){
      k_pwt<32><<<dim3(B, py), 256, 32*Ci*4, stream>>>(in, wg, bi, g, bt, o, Ci, Co, npix, inb, outb, post, slope);
    } else if (Co > 3){
      k_pwt<18><<<dim3(B, py), 256, 18*Ci*4, stream>>>(in, wg, bi, g, bt, o, Ci, Co, npix, inb, outb, post, slope);
    } else {
      k_pwt<3><<<dim3(B, py), 256, 3*Ci*4, stream>>>(in, wg, bi, g, bt, o, Ci, Co, npix, inb, outb, post, slope);
    }
  };
  auto MCONV = [&](const float* in, const float* in2, const unsigned short* wp, const float* bi,
                   const float* res, float* o, int B, int nblk, int dl, int lk){
    k_mconv<<<B*128, 256, 0, stream>>>(in, in2, wp, bi, res, o, nblk, dl, lk);
  };
  auto DILm = [&](const float* in, int set, const float* bset, int B){
    const unsigned short* w5 = wpkDB + (size_t)set*5*36864;
    MCONV(in, nullptr, w5,          bset,      nullptr, sA,   B, 1, 1, 1);
    MCONV(sA, nullptr, w5+36864,    bset+64,   nullptr, sB,   B, 1, 2, 1);
    MCONV(sB, nullptr, w5+2*36864,  bset+128,  nullptr, sA,   B, 1, 3, 1);
    MCONV(sA, nullptr, w5+3*36864,  bset+192,  nullptr, sB,   B, 1, 2, 1);
    MCONV(sB, nullptr, w5+4*36864,  bset+256,  in,      dbuf, B, 1, 1, 0);
  };
  auto DCONVm = [&](const float* in, int idx, float* o, int B){
    k_dwpw<4><<<B*128, 256, 0, stream>>>(in, cadw + idx*576, cadb + idx*64,
        pwpkCA + (size_t)idx*4096, capb + idx*64, o, 64, (size_t)64*HWn, 0);
  };
  auto ATTNm = [&](const float* qsrc, int qidx, float* o, int B){
    DCONVm(qsrc, qidx, qb, B);
    k_attn<<<B*128, 256, 0, stream>>>(qb, kb, vb, o);
  };
  auto PEMBEDm = [&](const float* in, float* outSlice, int B){
    k_dwpw<2><<<B*128, 256, 0, stream>>>(in, ctodw, nullptr, pwpkTO, nullptr,
        X, 18, (size_t)18*HWn, 1);
    k_defpw<<<B*128, 512, 0, stream>>>(in, X, ctdcn, pwpkTP, outSlice, 3, (size_t)6*HWn, 2);
  };

  // ===== Pack 3x3 conv weights + fdc weight transform =====
  k_pack<<<(552960 + 255)/256, 256, 0, stream>>>(dbw, wpkDB, 64, 36864, 552960);
  k_pack<<<288, 256, 0, stream>>>(hhw, wpkHH, 128, 73728, 73728);
  k_wfdc<<<104, 256, 0, stream>>>(fd1w, fd2w, fcw, fd1g, fd2g, wfdc);

  // ===== Phase 1: patch_embed(ch) -> h (3-channel, unfused path) =====
  k_dw3x3<<<dim3(36, Hn), 128, 0, stream>>>(xf, chodw, nullptr, dwb3, 3);
  PW(dwb3, chopw, nullptr, nullptr, nullptr, offb12, 12, 3, 18, HWn, 3*HWn, 18*HWn, 1, 0.f);
  k_deform<<<dim3(36, Hn), 128, 0, stream>>>(xf, offb12, chdcn, yb3, 3);
  PW(yb3, chpw, nullptr, nullptr, nullptr, h, 12, 3, 64, HWn, 3*HWn, 64*HWn, 2, 0.f);

  // ===== Phase 2: fft_block (wave-register 2-D FFT + fused branch chain) =====
  if (NB == 4){
    float* mB = P;                 // [12][64][8320]
    float* pB = P + 6389760;
    k_fft2<<<768, 512, 0, stream>>>(h, mB, pB);
    k_fdc<<<dim3(12, 130), 256, 0, stream>>>(mB, wfdc,         fd1bt,      fd2bt,      out1);
    k_fdc<<<dim3(12, 130), 256, 0, stream>>>(pB, wfdc + 13312, fd1bt + 32, fd2bt + 32, out2);
    k_ifft2<<<256, 512, 0, stream>>>(out1, out2, h, fftHL);
  } else {
    // 3 chunks of 4 batches (works for NB=1 and NB=2; pool >= 4.26M floats)
    float* mB = P;                 // [4][64][8320]
    float* pB = P + 2129920;
    for (int c=0; c<3; c++){
      const float* hsrc = h + (size_t)c*4*M;
      float* o1 = out1 + (size_t)c*2129920;
      float* o2 = out2 + (size_t)c*2129920;
      k_fft2<<<256, 512, 0, stream>>>(hsrc, mB, pB);
      k_fdc<<<dim3(4, 130), 256, 0, stream>>>(mB, wfdc,         fd1bt,      fd2bt,      o1);
      k_fdc<<<dim3(4, 130), 256, 0, stream>>>(pB, wfdc + 13312, fd1bt + 32, fd2bt + 32, o2);
      if (c == 0)
        k_ifft2<<<256, 512, 0, stream>>>(out1, out2, h, fftHL);
    }
  }

  // ===== Pack 1x1 pw weights (into pool slot; free after phase 2) =====
  k_packpw<<<96, 256, 0, stream>>>(capw,  pwpkCA, 64, 4, 24576);
  k_packpw<<<8,  256, 0, stream>>>(ctopw, pwpkTO, 18, 2, 2048);
  k_packpw<<<4,  256, 0, stream>>>(ctpw,  pwpkTP, 3,  1, 1024);

  // ===== Phases 3-5 in groups of NB batches =====
  for (int g0=0; g0<4; g0+=NB){
    const float* hHL = h + (size_t)g0*M;
    const float* hLH = h + (size_t)(4+g0)*M;
    const float* hHH = h + (size_t)(8+g0)*M;
    const float* fHL = fftHL + (size_t)g0*M;
    DCONVm(hHH, 1, kb, NB);
    DCONVm(hHH, 2, vb, NB);
    ATTNm(hLH, 0, aA, NB);                       // x_HH_LH (== f_HH_LH)
    DCONVm(hHH, 4, kb, NB);
    DCONVm(hHH, 5, vb, NB);
    ATTNm(hHL, 3, aB, NB);                       // x_HH_HL
    ATTNm(fHL, 3, aC, NB);                       // f_HH_HL
    // x_HH2 path
    MCONV(aA, aB, wpkHH, hhb, nullptr, hh1, NB, 2, 1, 0);
    DILm(hh1, 2, dbb + 2*320, NB);
    PEMBEDm(dbuf, cat6 + (size_t)((8+g0)*6)*HWn, NB);
    // f_HH2 path
    MCONV(aA, aC, wpkHH, hhb, nullptr, hh1, NB, 2, 1, 0);
    DILm(hh1, 2, dbb + 2*320, NB);
    PEMBEDm(dbuf, cat6 + (size_t)((8+g0)*6+3)*HWn, NB);
    // x_HL2 / x_LH2
    DILm(hHL, 1, dbb + 320, NB);
    PEMBEDm(dbuf, cat6 + (size_t)(g0*6)*HWn, NB);
    DILm(hLH, 0, dbb, NB);
    PEMBEDm(dbuf, cat6 + (size_t)((4+g0)*6)*HWn, NB);
    // fft_HL / fft_LH passthroughs
    PEMBEDm(fHL, cat6 + (size_t)(g0*6+3)*HWn, NB);
    PEMBEDm(hLH, cat6 + (size_t)((4+g0)*6+3)*HWn, NB);
  }

  // ===== Final conv + residual -> out0 =====
  k_conv3x3s<<<dim3(36, Hn), 128, 0, stream>>>(cat6, cw, cb, xf, out0, 6, 3);
}